// Round 8
// baseline (1098.898 us; speedup 1.0000x reference)
//
#include <hip/hip_runtime.h>
#include <cstdint>

// ---------------------------------------------------------------------------
// QRoPETRegressor: 4-layer transformer (B=32, S=520 w/ 8 cls, D=512, NH=8,
// HD=64, MLP=2048) + variational heads.
// R8: 8-wave GEMM (512 thr, per-wave 64x32), counted-vmcnt depth-2 pipeline.
// ---------------------------------------------------------------------------

#define BATCH   32
#define SEQ     520
#define SP      576
#define DIM     512
#define NHEAD   8
#define HDIM    64
#define MLPD    2048
#define NLAYER  4
#define NROW    (BATCH * SEQ)   // 16640
#define NPAIR   256

typedef __attribute__((ext_vector_type(4))) float  f32x4;
typedef __attribute__((ext_vector_type(8))) short  short8;

__device__ __forceinline__ unsigned short f2bf(float f) {
    unsigned u = __float_as_uint(f);
    unsigned r = (u + 0x7fffu + ((u >> 16) & 1u)) >> 16;
    return (unsigned short)r;
}
__device__ __forceinline__ float bf2f(short s) {
    return __uint_as_float(((unsigned)(unsigned short)s) << 16);
}
__device__ __forceinline__ unsigned cvt_pk_bf16(float lo, float hi) {
    unsigned r;
    asm("v_cvt_pk_bf16_f32 %0, %1, %2" : "=v"(r) : "v"(lo), "v"(hi));
    return r;
}
__device__ __forceinline__ float exp2_hw(float x) {
    float r;
    asm("v_exp_f32 %0, %1" : "=v"(r) : "v"(x));
    return r;
}
__device__ __forceinline__ float wred_sum(float v) {
    #pragma unroll
    for (int off = 32; off; off >>= 1) v += __shfl_xor(v, off);
    return v;
}

__device__ __forceinline__ void gload16(const void* g, void* l) {
    __builtin_amdgcn_global_load_lds(
        (const __attribute__((address_space(1))) unsigned int*)g,
        (__attribute__((address_space(3))) unsigned int*)l,
        16, 0, 0);
}

// ---------------------------------------------------------------------------
// Weight transpose-convert: src fp32 (K,N) -> dst bf16 (N,K)
// ---------------------------------------------------------------------------
__global__ __launch_bounds__(256) void k_wconv(const float* __restrict__ src,
                                               short* __restrict__ dst,
                                               int K, int N) {
    src += (size_t)blockIdx.z * K * N;
    dst += (size_t)blockIdx.z * K * N;
    int n0 = blockIdx.x * 64, k0 = blockIdx.y * 64;
    __shared__ float t[64][65];
    int tid = threadIdx.x;
    int r = tid >> 2, cq = (tid & 3) * 16;
    const float* sp = src + (size_t)(k0 + r) * N + n0 + cq;
    #pragma unroll
    for (int e = 0; e < 16; e += 4) {
        float4 v = *(const float4*)(sp + e);
        t[r][cq + e] = v.x; t[r][cq + e + 1] = v.y;
        t[r][cq + e + 2] = v.z; t[r][cq + e + 3] = v.w;
    }
    __syncthreads();
    int n = tid >> 2, kq = (tid & 3) * 16;
    short* dp = dst + (size_t)(n0 + n) * K + k0 + kq;
    unsigned o0[4], o1[4];
    #pragma unroll
    for (int e = 0; e < 4; e++)
        o0[e] = cvt_pk_bf16(t[kq + 2 * e][n], t[kq + 2 * e + 1][n]);
    #pragma unroll
    for (int e = 0; e < 4; e++)
        o1[e] = cvt_pk_bf16(t[kq + 8 + 2 * e][n], t[kq + 9 + 2 * e][n]);
    *(uint4*)dp = make_uint4(o0[0], o0[1], o0[2], o0[3]);
    *(uint4*)(dp + 8) = make_uint4(o1[0], o1[1], o1[2], o1[3]);
}

// ---------------------------------------------------------------------------
__global__ void k_rope_tab(float2* __restrict__ tab) {
    int s = blockIdx.x, i = threadIdx.x;
    float fr = powf(10000.f, -2.f * (float)i / 512.f);
    float th = (float)s * fr;
    float sn, cn;
    sincosf(th, &sn, &cn);
    tab[s * NPAIR + i] = make_float2(cn, sn);
}

// ---------------------------------------------------------------------------
// Input proj + cls concat -> bf16 h
// ---------------------------------------------------------------------------
__global__ __launch_bounds__(256) void k_in_proj(const float* __restrict__ x,
                                                 const float* __restrict__ Wi,
                                                 const float* __restrict__ bi,
                                                 const float* __restrict__ cls,
                                                 short* __restrict__ hb) {
    int row = blockIdx.x;
    int b = row / SEQ, s = row % SEQ;
    bool is_cls = s < 8;
    float xr[16];
    if (!is_cls) {
        const float* xp = x + (size_t)(b * 512 + (s - 8)) * 16;
        #pragma unroll
        for (int f = 0; f < 16; f++) xr[f] = xp[f];
    }
    for (int c = threadIdx.x; c < DIM; c += 256) {
        float v;
        if (is_cls) {
            v = cls[s * DIM + c];
        } else {
            v = bi[c];
            #pragma unroll
            for (int f = 0; f < 16; f++) v = fmaf(xr[f], Wi[f * DIM + c], v);
        }
        hb[(size_t)row * DIM + c] = (short)f2bf(v);
    }
}

// ---------------------------------------------------------------------------
// GEMM: C[M,N](bf16) = act(A @ W + bias [+ Res]), A bf16 [M][K], Bt [N][K].
// 128x128 tile, 8 waves (512 thr), per-wave 64x32 output (2M x 4N waves).
// Templated BK, dbuf LDS, counted-vmcnt depth-2:
//   vmcnt(NLD) -> barrier -> ds_read -> lgkmcnt(0) -> barrier -> stage(t+2)
//   -> MFMA.  Never vmcnt(0) mid-loop.  XOR-swizzled LDS, XCD-chunked order.
// ---------------------------------------------------------------------------
template <int BK, bool RELU, bool ADDRES>
__global__ __launch_bounds__(512) void k_gemm(const short* __restrict__ A,
                                              const short* __restrict__ Bt,
                                              const float* __restrict__ bias,
                                              const short* __restrict__ Res,
                                              short* __restrict__ Cout,
                                              int N, int K) {
    constexpr int NB  = BK / 8;        // 16B blocks per row (8 @BK64, 4 @BK32)
    constexpr int MSK = NB - 1;
    constexpr int RPW = 64 / NB;       // rows staged per wave per load
    constexpr int GPM = 128 / (8 * RPW);  // loads per matrix (2 @BK64, 1 @BK32)
    constexpr int NLD = 2 * GPM;       // gload16 per wave per stage (A+B)
    __shared__ __align__(16) short As[2][128 * BK];
    __shared__ __align__(16) short Bs[2][128 * BK];
    const int tid = threadIdx.x;
    const int w = tid >> 6, l = tid & 63;

    const int chunk = gridDim.x >> 3;
    const int t = (blockIdx.x & 7) * chunk + (blockIdx.x >> 3);
    const int C = N >> 7;
    const int brow = (t / C) * 128, bcol = (t % C) * 128;

    const int srow = l / NB;                // row within wave's RPW group
    const int sblk = l & MSK;
    const int soff = ((sblk ^ (srow & MSK)) * 8);
    const int fr = l & 15, t4 = l >> 4;
    const int wr = (w >> 2) * 64;           // wave row offset (2 M-groups)
    const int wc = (w & 3) * 32;            // wave col offset (4 N-groups)

    const short* Ab = A  + (size_t)(brow + w * RPW + srow) * K + soff;
    const short* Bb = Bt + (size_t)(bcol + w * RPW + srow) * K + soff;

    f32x4 acc[4][2];
    #pragma unroll
    for (int m = 0; m < 4; m++)
        #pragma unroll
        for (int n = 0; n < 2; n++) acc[m][n] = (f32x4){0.f, 0.f, 0.f, 0.f};

    auto stage = [&](int ko, int pb) {
        #pragma unroll
        for (int i = 0; i < GPM; i++)
            gload16(Ab + (size_t)(i * 8 * RPW) * K + ko,
                    &As[pb][(i * 8 * RPW + w * RPW) * BK]);
        #pragma unroll
        for (int i = 0; i < GPM; i++)
            gload16(Bb + (size_t)(i * 8 * RPW) * K + ko,
                    &Bs[pb][(i * 8 * RPW + w * RPW) * BK]);
    };

    const int nk = K / BK;
    stage(0, 0);
    stage(BK, 1);

    for (int kt = 0; kt < nk; ++kt) {
        const int cur = kt & 1;
        // wait for MY stage(kt); stage(kt+1) stays in flight
        if (kt + 1 < nk) {
            if constexpr (NLD == 4) asm volatile("s_waitcnt vmcnt(4)" ::: "memory");
            else                    asm volatile("s_waitcnt vmcnt(2)" ::: "memory");
        } else {
            asm volatile("s_waitcnt vmcnt(0)" ::: "memory");
        }
        __builtin_amdgcn_s_barrier();       // all waves' stage(kt) in LDS
        __builtin_amdgcn_sched_barrier(0);

        short8 af[4][BK / 32], bf[2][BK / 32];
        #pragma unroll
        for (int m = 0; m < 4; m++) {
            int r = wr + m * 16 + fr;
            #pragma unroll
            for (int kk = 0; kk < BK / 32; kk++)
                af[m][kk] = *(const short8*)
                    &As[cur][r * BK + (((kk * 4 + t4) ^ (r & MSK)) * 8)];
        }
        #pragma unroll
        for (int n = 0; n < 2; n++) {
            int r = wc + n * 16 + fr;
            #pragma unroll
            for (int kk = 0; kk < BK / 32; kk++)
                bf[n][kk] = *(const short8*)
                    &Bs[cur][r * BK + (((kk * 4 + t4) ^ (r & MSK)) * 8)];
        }
        asm volatile("s_waitcnt lgkmcnt(0)" ::: "memory");
        __builtin_amdgcn_s_barrier();       // all waves done reading [cur]
        __builtin_amdgcn_sched_barrier(0);
        if (kt + 2 < nk) stage((kt + 2) * BK, cur);

        __builtin_amdgcn_s_setprio(1);
        #pragma unroll
        for (int kk = 0; kk < BK / 32; kk++)
            #pragma unroll
            for (int m = 0; m < 4; m++)
                #pragma unroll
                for (int n = 0; n < 2; n++)
                    acc[m][n] = __builtin_amdgcn_mfma_f32_16x16x32_bf16(
                        af[m][kk], bf[n][kk], acc[m][n], 0, 0, 0);
        __builtin_amdgcn_s_setprio(0);
    }

    const int r0 = (l >> 4) * 4, c0 = l & 15;
    #pragma unroll
    for (int m = 0; m < 4; m++) {
        #pragma unroll
        for (int n = 0; n < 2; n++) {
            int col = bcol + wc + n * 16 + c0;
            float bv = bias[col];
            #pragma unroll
            for (int q = 0; q < 4; q++) {
                int row = brow + wr + m * 16 + r0 + q;
                float v = acc[m][n][q] + bv;
                if (ADDRES) v += bf2f(Res[(size_t)row * N + col]);
                if (RELU) v = fmaxf(v, 0.f);
                Cout[(size_t)row * N + col] = (short)f2bf(v);
            }
        }
    }
}

// ---------------------------------------------------------------------------
// K/V prep: rope K -> kbuf[bh][SP][64]; transpose V -> vtbuf[bh][64][SP].
// ---------------------------------------------------------------------------
__global__ __launch_bounds__(256) void k_kvprep(const short* __restrict__ qkv,
                                                const float2* __restrict__ tab,
                                                short* __restrict__ kbuf,
                                                short* __restrict__ vtbuf) {
    int bx = blockIdx.x;
    int jt = bx % 9, bh = bx / 9, b = bh >> 3, h = bh & 7;
    int tid = threadIdx.x;
    int row = tid >> 2, ch = tid & 3;
    int s = jt * 64 + row;
    bool valid = s < SEQ;
    size_t g = (size_t)(b * SEQ + (valid ? s : 0)) * 1536;

    short8 ok0 = (short8)0, ok1 = (short8)0;
    if (valid) {
        short8 k0 = *(const short8*)(qkv + g + 512 + h * 64 + ch * 16);
        short8 k1 = *(const short8*)(qkv + g + 512 + h * 64 + ch * 16 + 8);
        unsigned* u0 = (unsigned*)&ok0;
        unsigned* u1 = (unsigned*)&ok1;
        #pragma unroll
        for (int pp = 0; pp < 4; pp++) {
            float2 cs = tab[s * NPAIR + h * 32 + ch * 8 + pp];
            float x1 = bf2f(k0[2 * pp]), x2 = bf2f(k0[2 * pp + 1]);
            u0[pp] = cvt_pk_bf16(x1 * cs.x - x2 * cs.y, x1 * cs.y + x2 * cs.x);
            cs = tab[s * NPAIR + h * 32 + ch * 8 + 4 + pp];
            x1 = bf2f(k1[2 * pp]); x2 = bf2f(k1[2 * pp + 1]);
            u1[pp] = cvt_pk_bf16(x1 * cs.x - x2 * cs.y, x1 * cs.y + x2 * cs.x);
        }
    }
    short* kd = kbuf + ((size_t)bh * SP + jt * 64 + row) * 64 + ch * 16;
    *(short8*)kd = ok0;
    *(short8*)(kd + 8) = ok1;

    __shared__ short vt[64][72];
    short8 v0 = (short8)0, v1 = (short8)0;
    if (valid) {
        v0 = *(const short8*)(qkv + g + 1024 + h * 64 + ch * 16);
        v1 = *(const short8*)(qkv + g + 1024 + h * 64 + ch * 16 + 8);
    }
    *(short8*)&vt[row][ch * 16] = v0;
    *(short8*)&vt[row][ch * 16 + 8] = v1;
    __syncthreads();
    int d = row;
    short8 w0, w1;
    #pragma unroll
    for (int e = 0; e < 8; e++) w0[e] = vt[ch * 16 + e][d];
    #pragma unroll
    for (int e = 0; e < 8; e++) w1[e] = vt[ch * 16 + 8 + e][d];
    short* vd = vtbuf + ((size_t)bh * 64 + d) * SP + jt * 64 + ch * 16;
    *(short8*)vd = w0;
    *(short8*)(vd + 8) = w1;
}

// ---------------------------------------------------------------------------
// MFMA flash attention, counted-vmcnt depth-2 K/V pipeline, rope fused on Q.
// Softmax in log2 domain: defer-max (THR=8), per-lane deferred sum.
// grid: bx = qt*256 + bh
// ---------------------------------------------------------------------------
__global__ __launch_bounds__(256) void k_attn_mfma(const short* __restrict__ qkv,
                                                   const short* __restrict__ kbuf,
                                                   const short* __restrict__ vtbuf,
                                                   const float2* __restrict__ tab,
                                                   short* __restrict__ aob) {
    __shared__ __align__(16) short Kl[2][64 * 64];
    __shared__ __align__(16) short Vl[2][64 * 64];
    __shared__ __align__(16) short sP[4][16][72];
    const int tid = threadIdx.x;
    const int w = tid >> 6, l = tid & 63;
    const int c = l & 15, t4 = l >> 4;
    int bx = blockIdx.x;
    int qt = bx >> 8, bh = bx & 255, b = bh >> 3, h = bh & 7;

    // ---- Q fragments, rope fused, scaled by 0.125*log2(e) (exp2 domain) ----
    const float QSC = 0.125f * 1.44269504f;
    int q0 = qt * 64 + w * 16;
    int qrow = q0 + c;
    int qr = qrow < SEQ ? qrow : SEQ - 1;
    size_t gq = (size_t)(b * SEQ + qr) * 1536 + h * 64;
    short8 qf0 = *(const short8*)(qkv + gq + t4 * 8);
    short8 qf1 = *(const short8*)(qkv + gq + 32 + t4 * 8);
    {
        const float2* tq = tab + (size_t)qr * NPAIR + h * 32;
        unsigned* u0 = (unsigned*)&qf0;
        unsigned* u1 = (unsigned*)&qf1;
        #pragma unroll
        for (int pp = 0; pp < 4; pp++) {
            float2 cs = tq[t4 * 4 + pp];
            float x1 = bf2f(qf0[2 * pp]), x2 = bf2f(qf0[2 * pp + 1]);
            u0[pp] = cvt_pk_bf16((x1 * cs.x - x2 * cs.y) * QSC,
                                 (x1 * cs.y + x2 * cs.x) * QSC);
            cs = tq[16 + t4 * 4 + pp];
            x1 = bf2f(qf1[2 * pp]); x2 = bf2f(qf1[2 * pp + 1]);
            u1[pp] = cvt_pk_bf16((x1 * cs.x - x2 * cs.y) * QSC,
                                 (x1 * cs.y + x2 * cs.x) * QSC);
        }
    }

    f32x4 o0 = {0,0,0,0}, o1 = {0,0,0,0}, o2 = {0,0,0,0}, o3 = {0,0,0,0};
    float mrow[4] = {-1e30f, -1e30f, -1e30f, -1e30f};
    float lrow[4] = {0.f, 0.f, 0.f, 0.f};

    const short* kb = kbuf + (size_t)bh * SP * 64;
    const short* vb = vtbuf + (size_t)bh * 64 * SP;
    const int r1 = w * 16 + (l >> 3);
    const int r2 = r1 + 8;
    const int blk = l & 7;

    auto stage = [&](int jt, int pb) {
        gload16(kb + ((size_t)(jt * 64 + r1)) * 64 + ((blk ^ (r1 & 7)) * 8),
                &Kl[pb][(w * 16) * 64]);
        gload16(kb + ((size_t)(jt * 64 + r2)) * 64 + ((blk ^ (r2 & 7)) * 8),
                &Kl[pb][(w * 16 + 8) * 64]);
        gload16(vb + (size_t)r1 * SP + jt * 64 + ((blk ^ (r1 & 7)) * 8),
                &Vl[pb][(w * 16) * 64]);
        gload16(vb + (size_t)r2 * SP + jt * 64 + ((blk ^ (r2 & 7)) * 8),
                &Vl[pb][(w * 16 + 8) * 64]);
    };

    stage(0, 0);
    stage(1, 1);

    for (int jt = 0; jt < 9; jt++) {
        const int cur = jt & 1;
        if (jt + 1 < 9) asm volatile("s_waitcnt vmcnt(4)" ::: "memory");
        else            asm volatile("s_waitcnt vmcnt(0)" ::: "memory");
        __builtin_amdgcn_s_barrier();
        __builtin_amdgcn_sched_barrier(0);

        // ---- QK^T (scores in log2 domain)
        f32x4 s0 = {0,0,0,0}, s1 = {0,0,0,0}, s2 = {0,0,0,0}, s3 = {0,0,0,0};
        __builtin_amdgcn_s_setprio(1);
        {
            int kr0 = c, kr1 = 16 + c, kr2 = 32 + c, kr3 = 48 + c;
            short8 kf;
            kf = *(const short8*)&Kl[cur][kr0 * 64 + ((t4 ^ (kr0 & 7)) * 8)];
            s0 = __builtin_amdgcn_mfma_f32_16x16x32_bf16(qf0, kf, s0, 0, 0, 0);
            kf = *(const short8*)&Kl[cur][kr0 * 64 + (((4 + t4) ^ (kr0 & 7)) * 8)];
            s0 = __builtin_amdgcn_mfma_f32_16x16x32_bf16(qf1, kf, s0, 0, 0, 0);
            kf = *(const short8*)&Kl[cur][kr1 * 64 + ((t4 ^ (kr1 & 7)) * 8)];
            s1 = __builtin_amdgcn_mfma_f32_16x16x32_bf16(qf0, kf, s1, 0, 0, 0);
            kf = *(const short8*)&Kl[cur][kr1 * 64 + (((4 + t4) ^ (kr1 & 7)) * 8)];
            s1 = __builtin_amdgcn_mfma_f32_16x16x32_bf16(qf1, kf, s1, 0, 0, 0);
            kf = *(const short8*)&Kl[cur][kr2 * 64 + ((t4 ^ (kr2 & 7)) * 8)];
            s2 = __builtin_amdgcn_mfma_f32_16x16x32_bf16(qf0, kf, s2, 0, 0, 0);
            kf = *(const short8*)&Kl[cur][kr2 * 64 + (((4 + t4) ^ (kr2 & 7)) * 8)];
            s2 = __builtin_amdgcn_mfma_f32_16x16x32_bf16(qf1, kf, s2, 0, 0, 0);
            kf = *(const short8*)&Kl[cur][kr3 * 64 + ((t4 ^ (kr3 & 7)) * 8)];
            s3 = __builtin_amdgcn_mfma_f32_16x16x32_bf16(qf0, kf, s3, 0, 0, 0);
            kf = *(const short8*)&Kl[cur][kr3 * 64 + (((4 + t4) ^ (kr3 & 7)) * 8)];
            s3 = __builtin_amdgcn_mfma_f32_16x16x32_bf16(qf1, kf, s3, 0, 0, 0);
        }
        __builtin_amdgcn_s_setprio(0);

        if (jt == 8) {
            #pragma unroll
            for (int r = 0; r < 4; r++) {
                if (c >= 8) s0[r] = -1e30f;
                s1[r] = -1e30f; s2[r] = -1e30f; s3[r] = -1e30f;
            }
        }

        // ---- online softmax: defer-max (THR=8 in log2 domain), lazy sum
        #pragma unroll
        for (int r = 0; r < 4; r++) {
            float pmax = fmaxf(fmaxf(s0[r], s1[r]), fmaxf(s2[r], s3[r]));
            if (!__all(pmax <= mrow[r] + 8.f)) {
                float mx = pmax;
                mx = fmaxf(mx, __shfl_xor(mx, 1));
                mx = fmaxf(mx, __shfl_xor(mx, 2));
                mx = fmaxf(mx, __shfl_xor(mx, 4));
                mx = fmaxf(mx, __shfl_xor(mx, 8));
                if (mx > mrow[r]) {
                    float sc = exp2_hw(mrow[r] - mx);
                    mrow[r] = mx;
                    lrow[r] *= sc;
                    o0[r] *= sc; o1[r] *= sc; o2[r] *= sc; o3[r] *= sc;
                }
            }
            float p0 = exp2_hw(s0[r] - mrow[r]);
            float p1 = exp2_hw(s1[r] - mrow[r]);
            float p2 = exp2_hw(s2[r] - mrow[r]);
            float p3 = exp2_hw(s3[r] - mrow[r]);
            lrow[r] += (p0 + p1) + (p2 + p3);
            unsigned pk01 = cvt_pk_bf16(p0, p1);
            unsigned pk23 = cvt_pk_bf16(p2, p3);
            int q = t4 * 4 + r;
            sP[w][q][c]      = (short)(pk01 & 0xffff);
            sP[w][q][16 + c] = (short)(pk01 >> 16);
            sP[w][q][32 + c] = (short)(pk23 & 0xffff);
            sP[w][q][48 + c] = (short)(pk23 >> 16);
        }

        // ---- PV
        __builtin_amdgcn_s_setprio(1);
        {
            short8 pf0 = *(const short8*)&sP[w][c][t4 * 8];
            short8 pf1 = *(const short8*)&sP[w][c][32 + t4 * 8];
            int vr0 = c, vr1 = 16 + c, vr2 = 32 + c, vr3 = 48 + c;
            short8 vf;
            vf = *(const short8*)&Vl[cur][vr0 * 64 + ((t4 ^ (vr0 & 7)) * 8)];
            o0 = __builtin_amdgcn_mfma_f32_16x16x32_bf16(pf0, vf, o0, 0, 0, 0);
            vf = *(const short8*)&Vl[cur][vr0 * 64 + (((4 + t4) ^ (vr0 & 7)) * 8)];
            o0 = __builtin_amdgcn_mfma_f32_16x16x32_bf16(pf1, vf, o0, 0, 0, 0);
            vf = *(const short8*)&Vl[cur][vr1 * 64 + ((t4 ^ (vr1 & 7)) * 8)];
            o1 = __builtin_amdgcn_mfma_f32_16x16x32_bf16(pf0, vf, o1, 0, 0, 0);
            vf = *(const short8*)&Vl[cur][vr1 * 64 + (((4 + t4) ^ (vr1 & 7)) * 8)];
            o1 = __builtin_amdgcn_mfma_f32_16x16x32_bf16(pf1, vf, o1, 0, 0, 0);
            vf = *(const short8*)&Vl[cur][vr2 * 64 + ((t4 ^ (vr2 & 7)) * 8)];
            o2 = __builtin_amdgcn_mfma_f32_16x16x32_bf16(pf0, vf, o2, 0, 0, 0);
            vf = *(const short8*)&Vl[cur][vr2 * 64 + (((4 + t4) ^ (vr2 & 7)) * 8)];
            o2 = __builtin_amdgcn_mfma_f32_16x16x32_bf16(pf1, vf, o2, 0, 0, 0);
            vf = *(const short8*)&Vl[cur][vr3 * 64 + ((t4 ^ (vr3 & 7)) * 8)];
            o3 = __builtin_amdgcn_mfma_f32_16x16x32_bf16(pf0, vf, o3, 0, 0, 0);
            vf = *(const short8*)&Vl[cur][vr3 * 64 + (((4 + t4) ^ (vr3 & 7)) * 8)];
            o3 = __builtin_amdgcn_mfma_f32_16x16x32_bf16(pf1, vf, o3, 0, 0, 0);
        }
        __builtin_amdgcn_s_setprio(0);

        asm volatile("s_waitcnt lgkmcnt(0)" ::: "memory");
        __builtin_amdgcn_s_barrier();
        __builtin_amdgcn_sched_barrier(0);
        if (jt + 2 < 9) stage(jt + 2, cur);
    }

    // ---- epilogue
    #pragma unroll
    for (int r = 0; r < 4; r++) {
        float s = lrow[r];
        s += __shfl_xor(s, 1);
        s += __shfl_xor(s, 2);
        s += __shfl_xor(s, 4);
        s += __shfl_xor(s, 8);
        int q = q0 + t4 * 4 + r;
        if (q < SEQ) {
            float inv = 1.f / s;
            short* ao = aob + ((size_t)(b * SEQ + q)) * DIM + h * 64 + c;
            ao[0]  = (short)f2bf(o0[r] * inv);
            ao[16] = (short)f2bf(o1[r] * inv);
            ao[32] = (short)f2bf(o2[r] * inv);
            ao[48] = (short)f2bf(o3[r] * inv);
        }
    }
}

// ---------------------------------------------------------------------------
// LayerNorm (input already contains residual sum): hb = LN(sum)*g + b
// ---------------------------------------------------------------------------
__global__ __launch_bounds__(256) void k_ln(short* __restrict__ hb,
                                            const short* __restrict__ sum,
                                            const float* __restrict__ g,
                                            const float* __restrict__ bta) {
    int row = blockIdx.x * 4 + (threadIdx.x >> 6);
    int l = threadIdx.x & 63;
    size_t base = (size_t)row * DIM + l * 8;
    short8 hv = *(const short8*)&sum[base];
    float a[8];
    float s1 = 0.f, s2 = 0.f;
    #pragma unroll
    for (int e = 0; e < 8; e++) {
        a[e] = bf2f(hv[e]);
        s1 += a[e];
        s2 += a[e] * a[e];
    }
    s1 = wred_sum(s1);
    s2 = wred_sum(s2);
    float mu = s1 * (1.f / 512.f);
    float rr = rsqrtf(s2 * (1.f / 512.f) - mu * mu + 1e-6f);
    float4 g0 = *(const float4*)&g[l * 8];
    float4 g1 = *(const float4*)&g[l * 8 + 4];
    float4 b0 = *(const float4*)&bta[l * 8];
    float4 b1 = *(const float4*)&bta[l * 8 + 4];
    unsigned o[4];
    o[0] = cvt_pk_bf16((a[0] - mu) * rr * g0.x + b0.x,
                       (a[1] - mu) * rr * g0.y + b0.y);
    o[1] = cvt_pk_bf16((a[2] - mu) * rr * g0.z + b0.z,
                       (a[3] - mu) * rr * g0.w + b0.w);
    o[2] = cvt_pk_bf16((a[4] - mu) * rr * g1.x + b1.x,
                       (a[5] - mu) * rr * g1.y + b1.y);
    o[3] = cvt_pk_bf16((a[6] - mu) * rr * g1.z + b1.z,
                       (a[7] - mu) * rr * g1.w + b1.w);
    *(uint4*)&hb[base] = make_uint4(o[0], o[1], o[2], o[3]);
}

// ---------------------------------------------------------------------------
// Head hidden: hid[b,o,j] = relu(x_cls[b,o,:] @ Wh[o] + bh[o,j])
// ---------------------------------------------------------------------------
__global__ __launch_bounds__(256) void k_hid(const short* __restrict__ hb,
                                             const float* __restrict__ Wh,
                                             const float* __restrict__ bh,
                                             float* __restrict__ hid) {
    int j = blockIdx.x * 256 + threadIdx.x;
    int o = blockIdx.y, b = blockIdx.z;
    const short* xr = hb + ((size_t)(b * SEQ + o)) * DIM;
    const float* wcol = Wh + (size_t)o * DIM * DIM + j;
    float acc = bh[o * DIM + j];
    #pragma unroll 8
    for (int d = 0; d < DIM; d++)
        acc = fmaf(bf2f(xr[d]), wcol[(size_t)d * DIM], acc);
    hid[((size_t)b * 8 + o) * DIM + j] = fmaxf(acc, 0.f);
}

// ---------------------------------------------------------------------------
__device__ __forceinline__ float softplus_f(float x) { return log1pf(expf(x)); }

__global__ __launch_bounds__(64) void k_var(const float* __restrict__ hid,
                                            const float* __restrict__ mu_wmu,
                                            const float* __restrict__ mu_wrho,
                                            const float* __restrict__ mu_bmu,
                                            const float* __restrict__ mu_brho,
                                            const float* __restrict__ lv_wmu,
                                            const float* __restrict__ lv_wrho,
                                            const float* __restrict__ lv_bmu,
                                            const float* __restrict__ lv_brho,
                                            const float* __restrict__ eps_mu_w,
                                            const float* __restrict__ eps_mu_b,
                                            const float* __restrict__ eps_lv_w,
                                            const float* __restrict__ eps_lv_b,
                                            float* __restrict__ out) {
    const float EPS = 1e-8f;
    int bo = blockIdx.x;
    int o = bo & 7;
    int l = threadIdx.x;
    float am = 0.f, al = 0.f;
    #pragma unroll
    for (int k = 0; k < 8; k++) {
        int d = k * 64 + l;
        int od = o * DIM + d;
        float hv = hid[(size_t)bo * DIM + d];
        am = fmaf(hv, mu_wmu[od] + (softplus_f(mu_wrho[od]) + EPS) * eps_mu_w[od], am);
        al = fmaf(hv, lv_wmu[od] + (softplus_f(lv_wrho[od]) + EPS) * eps_lv_w[od], al);
    }
    am = wred_sum(am);
    al = wred_sum(al);
    if (l == 0) {
        float mu = am + mu_bmu[o] + (softplus_f(mu_brho[o]) + EPS) * eps_mu_b[o];
        out[bo] = mu;
        float lvv = al + lv_bmu[o] + (softplus_f(lv_brho[o]) + EPS) * eps_lv_b[o];
        out[256 + bo] = logf(EPS + softplus_f(lvv));
    }
}

// ---------------------------------------------------------------------------
extern "C" void kernel_launch(void* const* d_in, const int* in_sizes, int n_in,
                              void* d_out, int out_size, void* d_ws, size_t ws_size,
                              hipStream_t stream) {
    const float* x      = (const float*)d_in[0];
    const float* W_in   = (const float*)d_in[1];
    const float* b_in   = (const float*)d_in[2];
    const float* cls    = (const float*)d_in[3];
    const float* Wqkv   = (const float*)d_in[4];
    const float* bqkv   = (const float*)d_in[5];
    const float* Wo     = (const float*)d_in[6];
    const float* bo     = (const float*)d_in[7];
    const float* ln1_g  = (const float*)d_in[8];
    const float* ln1_b  = (const float*)d_in[9];
    const float* Wm1    = (const float*)d_in[10];
    const float* bm1    = (const float*)d_in[11];
    const float* Wm2    = (const float*)d_in[12];
    const float* bm2    = (const float*)d_in[13];
    const float* ln2_g  = (const float*)d_in[14];
    const float* ln2_b  = (const float*)d_in[15];
    const float* Wh     = (const float*)d_in[16];
    const float* bh     = (const float*)d_in[17];
    const float* mu_wmu = (const float*)d_in[18];
    const float* mu_wrho= (const float*)d_in[19];
    const float* mu_bmu = (const float*)d_in[20];
    const float* mu_brho= (const float*)d_in[21];
    const float* lv_wmu = (const float*)d_in[22];
    const float* lv_wrho= (const float*)d_in[23];
    const float* lv_bmu = (const float*)d_in[24];
    const float* lv_brho= (const float*)d_in[25];
    const float* e_mu_w = (const float*)d_in[26];
    const float* e_mu_b = (const float*)d_in[27];
    const float* e_lv_w = (const float*)d_in[28];
    const float* e_lv_b = (const float*)d_in[29];
    float* out = (float*)d_out;

    char* p = (char*)d_ws;
    auto alloc = [&](size_t bytes) {
        char* r = p;
        p += (bytes + 255) & ~(size_t)255;
        return r;
    };
    const size_t qkv_bytes = (size_t)NROW * 1536 * 2;
    const size_t kbuf_bytes = (size_t)BATCH * NHEAD * SP * 64 * 2;
    const size_t attn_bytes = qkv_bytes + 2 * kbuf_bytes + 512;
    const size_t mid_bytes = (size_t)NROW * MLPD * 2;
    char*   U1    =          alloc(attn_bytes > mid_bytes ? attn_bytes : mid_bytes);
    short*  qkv   = (short*)U1;
    short*  kbuf  = (short*)(U1 + ((qkv_bytes + 255) & ~(size_t)255));
    short*  vtbuf = kbuf + kbuf_bytes / 2;
    short*  mid   = (short*)U1;
    short*  hb    = (short*) alloc((size_t)NROW * DIM * 2);
    short*  deltab= (short*) alloc((size_t)NROW * DIM * 2);
    short*  aob   = (short*) alloc((size_t)NROW * DIM * 2);
    short*  wqkvt = (short*) alloc((size_t)NLAYER * 1536 * 512 * 2);
    short*  wot   = (short*) alloc((size_t)NLAYER * 512 * 512 * 2);
    short*  wm1t  = (short*) alloc((size_t)NLAYER * 2048 * 512 * 2);
    short*  wm2t  = (short*) alloc((size_t)NLAYER * 512 * 2048 * 2);
    float2* ropet = (float2*)alloc((size_t)SEQ * NPAIR * 8);
    float*  hid   = (float*) alloc((size_t)256 * DIM * 4);

    k_wconv<<<dim3(24, 8, 4), 256, 0, stream>>>(Wqkv, wqkvt, 512, 1536);
    k_wconv<<<dim3(8, 8, 4),  256, 0, stream>>>(Wo,   wot,   512, 512);
    k_wconv<<<dim3(32, 8, 4), 256, 0, stream>>>(Wm1,  wm1t,  512, 2048);
    k_wconv<<<dim3(8, 32, 4), 256, 0, stream>>>(Wm2,  wm2t,  2048, 512);
    k_rope_tab<<<SEQ, NPAIR, 0, stream>>>(ropet);
    k_in_proj<<<NROW, 256, 0, stream>>>(x, W_in, b_in, cls, hb);

    const int RT = NROW / 128;   // 130
    for (int l = 0; l < NLAYER; l++) {
        k_gemm<32, false, false><<<RT * 12, 512, 0, stream>>>(
            hb, wqkvt + (size_t)l * 1536 * 512, bqkv + l * 1536, nullptr, qkv, 1536, 512);
        k_kvprep<<<BATCH * NHEAD * 9, 256, 0, stream>>>(qkv, ropet, kbuf, vtbuf);
        k_attn_mfma<<<9 * 256, 256, 0, stream>>>(qkv, kbuf, vtbuf, ropet, aob);
        k_gemm<64, false, true><<<RT * 4, 512, 0, stream>>>(
            aob, wot + (size_t)l * 512 * 512, bo + l * 512, hb, deltab, 512, 512);
        k_ln<<<NROW / 4, 256, 0, stream>>>(hb, deltab, ln1_g + l * 512, ln1_b + l * 512);
        k_gemm<32, true, false><<<RT * 16, 512, 0, stream>>>(
            hb, wm1t + (size_t)l * 2048 * 512, bm1 + l * 2048, nullptr, mid, 2048, 512);
        k_gemm<64, false, true><<<RT * 4, 512, 0, stream>>>(
            mid, wm2t + (size_t)l * 512 * 2048, bm2 + l * 512, hb, deltab, 512, 2048);
        k_ln<<<NROW / 4, 256, 0, stream>>>(hb, deltab, ln2_g + l * 512, ln2_b + l * 512);
    }

    k_hid<<<dim3(2, 8, 32), 256, 0, stream>>>(hb, Wh, bh, hid);
    k_var<<<256, 64, 0, stream>>>(hid, mu_wmu, mu_wrho, mu_bmu, mu_brho,
                                  lv_wmu, lv_wrho, lv_bmu, lv_brho,
                                  e_mu_w, e_mu_b, e_lv_w, e_lv_b, out);
}

// Round 9
// 1072.569 us; speedup vs baseline: 1.0245x; 1.0245x over previous
//
#include <hip/hip_runtime.h>
#include <cstdint>

// ---------------------------------------------------------------------------
// QRoPETRegressor: 4-layer transformer (B=32, S=520 w/ 8 cls, D=512, NH=8,
// HD=64, MLP=2048) + variational heads.
// R9: N=512 GEMMs (Wo, MLP2) -> 128x64 tiles, 4 waves, 4+ blocks/CU
//     (more independent barrier domains per CU).  qkv/MLP1 keep 128x128.
// ---------------------------------------------------------------------------

#define BATCH   32
#define SEQ     520
#define SP      576
#define DIM     512
#define NHEAD   8
#define HDIM    64
#define MLPD    2048
#define NLAYER  4
#define NROW    (BATCH * SEQ)   // 16640
#define NPAIR   256

typedef __attribute__((ext_vector_type(4))) float  f32x4;
typedef __attribute__((ext_vector_type(8))) short  short8;

__device__ __forceinline__ unsigned short f2bf(float f) {
    unsigned u = __float_as_uint(f);
    unsigned r = (u + 0x7fffu + ((u >> 16) & 1u)) >> 16;
    return (unsigned short)r;
}
__device__ __forceinline__ float bf2f(short s) {
    return __uint_as_float(((unsigned)(unsigned short)s) << 16);
}
__device__ __forceinline__ unsigned cvt_pk_bf16(float lo, float hi) {
    unsigned r;
    asm("v_cvt_pk_bf16_f32 %0, %1, %2" : "=v"(r) : "v"(lo), "v"(hi));
    return r;
}
__device__ __forceinline__ float exp2_hw(float x) {
    float r;
    asm("v_exp_f32 %0, %1" : "=v"(r) : "v"(x));
    return r;
}
__device__ __forceinline__ float wred_sum(float v) {
    #pragma unroll
    for (int off = 32; off; off >>= 1) v += __shfl_xor(v, off);
    return v;
}

__device__ __forceinline__ void gload16(const void* g, void* l) {
    __builtin_amdgcn_global_load_lds(
        (const __attribute__((address_space(1))) unsigned int*)g,
        (__attribute__((address_space(3))) unsigned int*)l,
        16, 0, 0);
}

// ---------------------------------------------------------------------------
// Weight transpose-convert: src fp32 (K,N) -> dst bf16 (N,K)
// ---------------------------------------------------------------------------
__global__ __launch_bounds__(256) void k_wconv(const float* __restrict__ src,
                                               short* __restrict__ dst,
                                               int K, int N) {
    src += (size_t)blockIdx.z * K * N;
    dst += (size_t)blockIdx.z * K * N;
    int n0 = blockIdx.x * 64, k0 = blockIdx.y * 64;
    __shared__ float t[64][65];
    int tid = threadIdx.x;
    int r = tid >> 2, cq = (tid & 3) * 16;
    const float* sp = src + (size_t)(k0 + r) * N + n0 + cq;
    #pragma unroll
    for (int e = 0; e < 16; e += 4) {
        float4 v = *(const float4*)(sp + e);
        t[r][cq + e] = v.x; t[r][cq + e + 1] = v.y;
        t[r][cq + e + 2] = v.z; t[r][cq + e + 3] = v.w;
    }
    __syncthreads();
    int n = tid >> 2, kq = (tid & 3) * 16;
    short* dp = dst + (size_t)(n0 + n) * K + k0 + kq;
    unsigned o0[4], o1[4];
    #pragma unroll
    for (int e = 0; e < 4; e++)
        o0[e] = cvt_pk_bf16(t[kq + 2 * e][n], t[kq + 2 * e + 1][n]);
    #pragma unroll
    for (int e = 0; e < 4; e++)
        o1[e] = cvt_pk_bf16(t[kq + 8 + 2 * e][n], t[kq + 9 + 2 * e][n]);
    *(uint4*)dp = make_uint4(o0[0], o0[1], o0[2], o0[3]);
    *(uint4*)(dp + 8) = make_uint4(o1[0], o1[1], o1[2], o1[3]);
}

// ---------------------------------------------------------------------------
__global__ void k_rope_tab(float2* __restrict__ tab) {
    int s = blockIdx.x, i = threadIdx.x;
    float fr = powf(10000.f, -2.f * (float)i / 512.f);
    float th = (float)s * fr;
    float sn, cn;
    sincosf(th, &sn, &cn);
    tab[s * NPAIR + i] = make_float2(cn, sn);
}

// ---------------------------------------------------------------------------
// Input proj + cls concat -> bf16 h
// ---------------------------------------------------------------------------
__global__ __launch_bounds__(256) void k_in_proj(const float* __restrict__ x,
                                                 const float* __restrict__ Wi,
                                                 const float* __restrict__ bi,
                                                 const float* __restrict__ cls,
                                                 short* __restrict__ hb) {
    int row = blockIdx.x;
    int b = row / SEQ, s = row % SEQ;
    bool is_cls = s < 8;
    float xr[16];
    if (!is_cls) {
        const float* xp = x + (size_t)(b * 512 + (s - 8)) * 16;
        #pragma unroll
        for (int f = 0; f < 16; f++) xr[f] = xp[f];
    }
    for (int c = threadIdx.x; c < DIM; c += 256) {
        float v;
        if (is_cls) {
            v = cls[s * DIM + c];
        } else {
            v = bi[c];
            #pragma unroll
            for (int f = 0; f < 16; f++) v = fmaf(xr[f], Wi[f * DIM + c], v);
        }
        hb[(size_t)row * DIM + c] = (short)f2bf(v);
    }
}

// ---------------------------------------------------------------------------
// GEMM (128x128 tile, 8 waves): for N >= 1024 shapes (qkv, MLP1).
// Counted-vmcnt depth-2, XOR-swizzle, XCD-chunked tile order.
// ---------------------------------------------------------------------------
template <int BK, bool RELU, bool ADDRES>
__global__ __launch_bounds__(512) void k_gemm(const short* __restrict__ A,
                                              const short* __restrict__ Bt,
                                              const float* __restrict__ bias,
                                              const short* __restrict__ Res,
                                              short* __restrict__ Cout,
                                              int N, int K) {
    constexpr int NB  = BK / 8;
    constexpr int MSK = NB - 1;
    constexpr int RPW = 64 / NB;          // rows per gload16
    constexpr int GPM = 128 / (8 * RPW);  // loads per matrix per wave
    constexpr int NLD = 2 * GPM;
    __shared__ __align__(16) short As[2][128 * BK];
    __shared__ __align__(16) short Bs[2][128 * BK];
    const int tid = threadIdx.x;
    const int w = tid >> 6, l = tid & 63;

    const int chunk = gridDim.x >> 3;
    const int t = (blockIdx.x & 7) * chunk + (blockIdx.x >> 3);
    const int C = N >> 7;
    const int brow = (t / C) * 128, bcol = (t % C) * 128;

    const int srow = l / NB;
    const int sblk = l & MSK;
    const int soff = ((sblk ^ (srow & MSK)) * 8);
    const int fr = l & 15, t4 = l >> 4;
    const int wr = (w >> 2) * 64;
    const int wc = (w & 3) * 32;

    const short* Ab = A  + (size_t)(brow + w * RPW + srow) * K + soff;
    const short* Bb = Bt + (size_t)(bcol + w * RPW + srow) * K + soff;

    f32x4 acc[4][2];
    #pragma unroll
    for (int m = 0; m < 4; m++)
        #pragma unroll
        for (int n = 0; n < 2; n++) acc[m][n] = (f32x4){0.f, 0.f, 0.f, 0.f};

    auto stage = [&](int ko, int pb) {
        #pragma unroll
        for (int i = 0; i < GPM; i++)
            gload16(Ab + (size_t)(i * 8 * RPW) * K + ko,
                    &As[pb][(i * 8 * RPW + w * RPW) * BK]);
        #pragma unroll
        for (int i = 0; i < GPM; i++)
            gload16(Bb + (size_t)(i * 8 * RPW) * K + ko,
                    &Bs[pb][(i * 8 * RPW + w * RPW) * BK]);
    };

    const int nk = K / BK;
    stage(0, 0);
    stage(BK, 1);

    for (int kt = 0; kt < nk; ++kt) {
        const int cur = kt & 1;
        if (kt + 1 < nk) {
            if constexpr (NLD == 4) asm volatile("s_waitcnt vmcnt(4)" ::: "memory");
            else                    asm volatile("s_waitcnt vmcnt(2)" ::: "memory");
        } else {
            asm volatile("s_waitcnt vmcnt(0)" ::: "memory");
        }
        __builtin_amdgcn_s_barrier();
        __builtin_amdgcn_sched_barrier(0);

        short8 af[4][BK / 32], bf[2][BK / 32];
        #pragma unroll
        for (int m = 0; m < 4; m++) {
            int r = wr + m * 16 + fr;
            #pragma unroll
            for (int kk = 0; kk < BK / 32; kk++)
                af[m][kk] = *(const short8*)
                    &As[cur][r * BK + (((kk * 4 + t4) ^ (r & MSK)) * 8)];
        }
        #pragma unroll
        for (int n = 0; n < 2; n++) {
            int r = wc + n * 16 + fr;
            #pragma unroll
            for (int kk = 0; kk < BK / 32; kk++)
                bf[n][kk] = *(const short8*)
                    &Bs[cur][r * BK + (((kk * 4 + t4) ^ (r & MSK)) * 8)];
        }
        asm volatile("s_waitcnt lgkmcnt(0)" ::: "memory");
        __builtin_amdgcn_s_barrier();
        __builtin_amdgcn_sched_barrier(0);
        if (kt + 2 < nk) stage((kt + 2) * BK, cur);

        __builtin_amdgcn_s_setprio(1);
        #pragma unroll
        for (int kk = 0; kk < BK / 32; kk++)
            #pragma unroll
            for (int m = 0; m < 4; m++)
                #pragma unroll
                for (int n = 0; n < 2; n++)
                    acc[m][n] = __builtin_amdgcn_mfma_f32_16x16x32_bf16(
                        af[m][kk], bf[n][kk], acc[m][n], 0, 0, 0);
        __builtin_amdgcn_s_setprio(0);
    }

    const int r0 = (l >> 4) * 4, c0 = l & 15;
    #pragma unroll
    for (int m = 0; m < 4; m++) {
        #pragma unroll
        for (int n = 0; n < 2; n++) {
            int col = bcol + wc + n * 16 + c0;
            float bv = bias[col];
            #pragma unroll
            for (int q = 0; q < 4; q++) {
                int row = brow + wr + m * 16 + r0 + q;
                float v = acc[m][n][q] + bv;
                if (ADDRES) v += bf2f(Res[(size_t)row * N + col]);
                if (RELU) v = fmaxf(v, 0.f);
                Cout[(size_t)row * N + col] = (short)f2bf(v);
            }
        }
    }
}

// ---------------------------------------------------------------------------
// GEMM (128x64 tile, 4 waves): for N=512 shapes (Wo, MLP2).
// grid = (M/128)*(N/64) blocks of 256 -> ~4 blocks/CU, 4 barrier domains.
// Same counted-vmcnt depth-2 structure.
// ---------------------------------------------------------------------------
template <int BK, bool RELU, bool ADDRES>
__global__ __launch_bounds__(256) void k_gemm64(const short* __restrict__ A,
                                                const short* __restrict__ Bt,
                                                const float* __restrict__ bias,
                                                const short* __restrict__ Res,
                                                short* __restrict__ Cout,
                                                int N, int K) {
    constexpr int NB  = BK / 8;
    constexpr int MSK = NB - 1;
    constexpr int RPL = 512 / BK;       // rows per gload16 (16 @32, 8 @64)
    constexpr int ALW = 128 / (4 * RPL);// A loads per wave (2 @32, 4 @64)
    constexpr int BLW = 64 / (4 * RPL); // B loads per wave (1 @32, 2 @64)
    constexpr int NLD = ALW + BLW;      // 3 or 6
    __shared__ __align__(16) short As[2][128 * BK];
    __shared__ __align__(16) short Bs[2][64 * BK];
    const int tid = threadIdx.x;
    const int w = tid >> 6, l = tid & 63;

    const int chunk = gridDim.x >> 3;
    const int t = (blockIdx.x & 7) * chunk + (blockIdx.x >> 3);
    const int C = N >> 6;
    const int brow = (t / C) * 128, bcol = (t % C) * 64;

    const int srow = l / NB;
    const int sblk = l & MSK;
    const int soff = ((sblk ^ (srow & MSK)) * 8);
    const int fr = l & 15, t4 = l >> 4;
    const int wr = (w >> 1) * 64;       // 2 M-groups of 64
    const int wc = (w & 1) * 32;        // 2 N-groups of 32

    f32x4 acc[4][2];
    #pragma unroll
    for (int m = 0; m < 4; m++)
        #pragma unroll
        for (int n = 0; n < 2; n++) acc[m][n] = (f32x4){0.f, 0.f, 0.f, 0.f};

    auto stage = [&](int ko, int pb) {
        #pragma unroll
        for (int i = 0; i < ALW; i++)
            gload16(A + (size_t)(brow + (w * ALW + i) * RPL + srow) * K + ko + soff,
                    &As[pb][((w * ALW + i) * RPL) * BK]);
        #pragma unroll
        for (int i = 0; i < BLW; i++)
            gload16(Bt + (size_t)(bcol + (w * BLW + i) * RPL + srow) * K + ko + soff,
                    &Bs[pb][((w * BLW + i) * RPL) * BK]);
    };

    const int nk = K / BK;
    stage(0, 0);
    stage(BK, 1);

    for (int kt = 0; kt < nk; ++kt) {
        const int cur = kt & 1;
        if (kt + 1 < nk) {
            if constexpr (NLD == 3) asm volatile("s_waitcnt vmcnt(3)" ::: "memory");
            else                    asm volatile("s_waitcnt vmcnt(6)" ::: "memory");
        } else {
            asm volatile("s_waitcnt vmcnt(0)" ::: "memory");
        }
        __builtin_amdgcn_s_barrier();
        __builtin_amdgcn_sched_barrier(0);

        short8 af[4][BK / 32], bf[2][BK / 32];
        #pragma unroll
        for (int m = 0; m < 4; m++) {
            int r = wr + m * 16 + fr;
            #pragma unroll
            for (int kk = 0; kk < BK / 32; kk++)
                af[m][kk] = *(const short8*)
                    &As[cur][r * BK + (((kk * 4 + t4) ^ (r & MSK)) * 8)];
        }
        #pragma unroll
        for (int n = 0; n < 2; n++) {
            int r = wc + n * 16 + fr;
            #pragma unroll
            for (int kk = 0; kk < BK / 32; kk++)
                bf[n][kk] = *(const short8*)
                    &Bs[cur][r * BK + (((kk * 4 + t4) ^ (r & MSK)) * 8)];
        }
        asm volatile("s_waitcnt lgkmcnt(0)" ::: "memory");
        __builtin_amdgcn_s_barrier();
        __builtin_amdgcn_sched_barrier(0);
        if (kt + 2 < nk) stage((kt + 2) * BK, cur);

        __builtin_amdgcn_s_setprio(1);
        #pragma unroll
        for (int kk = 0; kk < BK / 32; kk++)
            #pragma unroll
            for (int m = 0; m < 4; m++)
                #pragma unroll
                for (int n = 0; n < 2; n++)
                    acc[m][n] = __builtin_amdgcn_mfma_f32_16x16x32_bf16(
                        af[m][kk], bf[n][kk], acc[m][n], 0, 0, 0);
        __builtin_amdgcn_s_setprio(0);
    }

    const int r0 = (l >> 4) * 4, c0 = l & 15;
    #pragma unroll
    for (int m = 0; m < 4; m++) {
        #pragma unroll
        for (int n = 0; n < 2; n++) {
            int col = bcol + wc + n * 16 + c0;
            float bv = bias[col];
            #pragma unroll
            for (int q = 0; q < 4; q++) {
                int row = brow + wr + m * 16 + r0 + q;
                float v = acc[m][n][q] + bv;
                if (ADDRES) v += bf2f(Res[(size_t)row * N + col]);
                if (RELU) v = fmaxf(v, 0.f);
                Cout[(size_t)row * N + col] = (short)f2bf(v);
            }
        }
    }
}

// ---------------------------------------------------------------------------
// K/V prep: rope K -> kbuf[bh][SP][64]; transpose V -> vtbuf[bh][64][SP].
// ---------------------------------------------------------------------------
__global__ __launch_bounds__(256) void k_kvprep(const short* __restrict__ qkv,
                                                const float2* __restrict__ tab,
                                                short* __restrict__ kbuf,
                                                short* __restrict__ vtbuf) {
    int bx = blockIdx.x;
    int jt = bx % 9, bh = bx / 9, b = bh >> 3, h = bh & 7;
    int tid = threadIdx.x;
    int row = tid >> 2, ch = tid & 3;
    int s = jt * 64 + row;
    bool valid = s < SEQ;
    size_t g = (size_t)(b * SEQ + (valid ? s : 0)) * 1536;

    short8 ok0 = (short8)0, ok1 = (short8)0;
    if (valid) {
        short8 k0 = *(const short8*)(qkv + g + 512 + h * 64 + ch * 16);
        short8 k1 = *(const short8*)(qkv + g + 512 + h * 64 + ch * 16 + 8);
        unsigned* u0 = (unsigned*)&ok0;
        unsigned* u1 = (unsigned*)&ok1;
        #pragma unroll
        for (int pp = 0; pp < 4; pp++) {
            float2 cs = tab[s * NPAIR + h * 32 + ch * 8 + pp];
            float x1 = bf2f(k0[2 * pp]), x2 = bf2f(k0[2 * pp + 1]);
            u0[pp] = cvt_pk_bf16(x1 * cs.x - x2 * cs.y, x1 * cs.y + x2 * cs.x);
            cs = tab[s * NPAIR + h * 32 + ch * 8 + 4 + pp];
            x1 = bf2f(k1[2 * pp]); x2 = bf2f(k1[2 * pp + 1]);
            u1[pp] = cvt_pk_bf16(x1 * cs.x - x2 * cs.y, x1 * cs.y + x2 * cs.x);
        }
    }
    short* kd = kbuf + ((size_t)bh * SP + jt * 64 + row) * 64 + ch * 16;
    *(short8*)kd = ok0;
    *(short8*)(kd + 8) = ok1;

    __shared__ short vt[64][72];
    short8 v0 = (short8)0, v1 = (short8)0;
    if (valid) {
        v0 = *(const short8*)(qkv + g + 1024 + h * 64 + ch * 16);
        v1 = *(const short8*)(qkv + g + 1024 + h * 64 + ch * 16 + 8);
    }
    *(short8*)&vt[row][ch * 16] = v0;
    *(short8*)&vt[row][ch * 16 + 8] = v1;
    __syncthreads();
    int d = row;
    short8 w0, w1;
    #pragma unroll
    for (int e = 0; e < 8; e++) w0[e] = vt[ch * 16 + e][d];
    #pragma unroll
    for (int e = 0; e < 8; e++) w1[e] = vt[ch * 16 + 8 + e][d];
    short* vd = vtbuf + ((size_t)bh * 64 + d) * SP + jt * 64 + ch * 16;
    *(short8*)vd = w0;
    *(short8*)(vd + 8) = w1;
}

// ---------------------------------------------------------------------------
// MFMA flash attention, counted-vmcnt depth-2 K/V pipeline, rope fused on Q.
// grid: bx = qt*256 + bh
// ---------------------------------------------------------------------------
__global__ __launch_bounds__(256) void k_attn_mfma(const short* __restrict__ qkv,
                                                   const short* __restrict__ kbuf,
                                                   const short* __restrict__ vtbuf,
                                                   const float2* __restrict__ tab,
                                                   short* __restrict__ aob) {
    __shared__ __align__(16) short Kl[2][64 * 64];
    __shared__ __align__(16) short Vl[2][64 * 64];
    __shared__ __align__(16) short sP[4][16][72];
    const int tid = threadIdx.x;
    const int w = tid >> 6, l = tid & 63;
    const int c = l & 15, t4 = l >> 4;
    int bx = blockIdx.x;
    int qt = bx >> 8, bh = bx & 255, b = bh >> 3, h = bh & 7;

    const float QSC = 0.125f * 1.44269504f;
    int q0 = qt * 64 + w * 16;
    int qrow = q0 + c;
    int qr = qrow < SEQ ? qrow : SEQ - 1;
    size_t gq = (size_t)(b * SEQ + qr) * 1536 + h * 64;
    short8 qf0 = *(const short8*)(qkv + gq + t4 * 8);
    short8 qf1 = *(const short8*)(qkv + gq + 32 + t4 * 8);
    {
        const float2* tq = tab + (size_t)qr * NPAIR + h * 32;
        unsigned* u0 = (unsigned*)&qf0;
        unsigned* u1 = (unsigned*)&qf1;
        #pragma unroll
        for (int pp = 0; pp < 4; pp++) {
            float2 cs = tq[t4 * 4 + pp];
            float x1 = bf2f(qf0[2 * pp]), x2 = bf2f(qf0[2 * pp + 1]);
            u0[pp] = cvt_pk_bf16((x1 * cs.x - x2 * cs.y) * QSC,
                                 (x1 * cs.y + x2 * cs.x) * QSC);
            cs = tq[16 + t4 * 4 + pp];
            x1 = bf2f(qf1[2 * pp]); x2 = bf2f(qf1[2 * pp + 1]);
            u1[pp] = cvt_pk_bf16((x1 * cs.x - x2 * cs.y) * QSC,
                                 (x1 * cs.y + x2 * cs.x) * QSC);
        }
    }

    f32x4 o0 = {0,0,0,0}, o1 = {0,0,0,0}, o2 = {0,0,0,0}, o3 = {0,0,0,0};
    float mrow[4] = {-1e30f, -1e30f, -1e30f, -1e30f};
    float lrow[4] = {0.f, 0.f, 0.f, 0.f};

    const short* kb = kbuf + (size_t)bh * SP * 64;
    const short* vb = vtbuf + (size_t)bh * 64 * SP;
    const int r1 = w * 16 + (l >> 3);
    const int r2 = r1 + 8;
    const int blk = l & 7;

    auto stage = [&](int jt, int pb) {
        gload16(kb + ((size_t)(jt * 64 + r1)) * 64 + ((blk ^ (r1 & 7)) * 8),
                &Kl[pb][(w * 16) * 64]);
        gload16(kb + ((size_t)(jt * 64 + r2)) * 64 + ((blk ^ (r2 & 7)) * 8),
                &Kl[pb][(w * 16 + 8) * 64]);
        gload16(vb + (size_t)r1 * SP + jt * 64 + ((blk ^ (r1 & 7)) * 8),
                &Vl[pb][(w * 16) * 64]);
        gload16(vb + (size_t)r2 * SP + jt * 64 + ((blk ^ (r2 & 7)) * 8),
                &Vl[pb][(w * 16 + 8) * 64]);
    };

    stage(0, 0);
    stage(1, 1);

    for (int jt = 0; jt < 9; jt++) {
        const int cur = jt & 1;
        if (jt + 1 < 9) asm volatile("s_waitcnt vmcnt(4)" ::: "memory");
        else            asm volatile("s_waitcnt vmcnt(0)" ::: "memory");
        __builtin_amdgcn_s_barrier();
        __builtin_amdgcn_sched_barrier(0);

        f32x4 s0 = {0,0,0,0}, s1 = {0,0,0,0}, s2 = {0,0,0,0}, s3 = {0,0,0,0};
        __builtin_amdgcn_s_setprio(1);
        {
            int kr0 = c, kr1 = 16 + c, kr2 = 32 + c, kr3 = 48 + c;
            short8 kf;
            kf = *(const short8*)&Kl[cur][kr0 * 64 + ((t4 ^ (kr0 & 7)) * 8)];
            s0 = __builtin_amdgcn_mfma_f32_16x16x32_bf16(qf0, kf, s0, 0, 0, 0);
            kf = *(const short8*)&Kl[cur][kr0 * 64 + (((4 + t4) ^ (kr0 & 7)) * 8)];
            s0 = __builtin_amdgcn_mfma_f32_16x16x32_bf16(qf1, kf, s0, 0, 0, 0);
            kf = *(const short8*)&Kl[cur][kr1 * 64 + ((t4 ^ (kr1 & 7)) * 8)];
            s1 = __builtin_amdgcn_mfma_f32_16x16x32_bf16(qf0, kf, s1, 0, 0, 0);
            kf = *(const short8*)&Kl[cur][kr1 * 64 + (((4 + t4) ^ (kr1 & 7)) * 8)];
            s1 = __builtin_amdgcn_mfma_f32_16x16x32_bf16(qf1, kf, s1, 0, 0, 0);
            kf = *(const short8*)&Kl[cur][kr2 * 64 + ((t4 ^ (kr2 & 7)) * 8)];
            s2 = __builtin_amdgcn_mfma_f32_16x16x32_bf16(qf0, kf, s2, 0, 0, 0);
            kf = *(const short8*)&Kl[cur][kr2 * 64 + (((4 + t4) ^ (kr2 & 7)) * 8)];
            s2 = __builtin_amdgcn_mfma_f32_16x16x32_bf16(qf1, kf, s2, 0, 0, 0);
            kf = *(const short8*)&Kl[cur][kr3 * 64 + ((t4 ^ (kr3 & 7)) * 8)];
            s3 = __builtin_amdgcn_mfma_f32_16x16x32_bf16(qf0, kf, s3, 0, 0, 0);
            kf = *(const short8*)&Kl[cur][kr3 * 64 + (((4 + t4) ^ (kr3 & 7)) * 8)];
            s3 = __builtin_amdgcn_mfma_f32_16x16x32_bf16(qf1, kf, s3, 0, 0, 0);
        }
        __builtin_amdgcn_s_setprio(0);

        if (jt == 8) {
            #pragma unroll
            for (int r = 0; r < 4; r++) {
                if (c >= 8) s0[r] = -1e30f;
                s1[r] = -1e30f; s2[r] = -1e30f; s3[r] = -1e30f;
            }
        }

        #pragma unroll
        for (int r = 0; r < 4; r++) {
            float pmax = fmaxf(fmaxf(s0[r], s1[r]), fmaxf(s2[r], s3[r]));
            if (!__all(pmax <= mrow[r] + 8.f)) {
                float mx = pmax;
                mx = fmaxf(mx, __shfl_xor(mx, 1));
                mx = fmaxf(mx, __shfl_xor(mx, 2));
                mx = fmaxf(mx, __shfl_xor(mx, 4));
                mx = fmaxf(mx, __shfl_xor(mx, 8));
                if (mx > mrow[r]) {
                    float sc = exp2_hw(mrow[r] - mx);
                    mrow[r] = mx;
                    lrow[r] *= sc;
                    o0[r] *= sc; o1[r] *= sc; o2[r] *= sc; o3[r] *= sc;
                }
            }
            float p0 = exp2_hw(s0[r] - mrow[r]);
            float p1 = exp2_hw(s1[r] - mrow[r]);
            float p2 = exp2_hw(s2[r] - mrow[r]);
            float p3 = exp2_hw(s3[r] - mrow[r]);
            lrow[r] += (p0 + p1) + (p2 + p3);
            unsigned pk01 = cvt_pk_bf16(p0, p1);
            unsigned pk23 = cvt_pk_bf16(p2, p3);
            int q = t4 * 4 + r;
            sP[w][q][c]      = (short)(pk01 & 0xffff);
            sP[w][q][16 + c] = (short)(pk01 >> 16);
            sP[w][q][32 + c] = (short)(pk23 & 0xffff);
            sP[w][q][48 + c] = (short)(pk23 >> 16);
        }

        __builtin_amdgcn_s_setprio(1);
        {
            short8 pf0 = *(const short8*)&sP[w][c][t4 * 8];
            short8 pf1 = *(const short8*)&sP[w][c][32 + t4 * 8];
            int vr0 = c, vr1 = 16 + c, vr2 = 32 + c, vr3 = 48 + c;
            short8 vf;
            vf = *(const short8*)&Vl[cur][vr0 * 64 + ((t4 ^ (vr0 & 7)) * 8)];
            o0 = __builtin_amdgcn_mfma_f32_16x16x32_bf16(pf0, vf, o0, 0, 0, 0);
            vf = *(const short8*)&Vl[cur][vr0 * 64 + (((4 + t4) ^ (vr0 & 7)) * 8)];
            o0 = __builtin_amdgcn_mfma_f32_16x16x32_bf16(pf1, vf, o0, 0, 0, 0);
            vf = *(const short8*)&Vl[cur][vr1 * 64 + ((t4 ^ (vr1 & 7)) * 8)];
            o1 = __builtin_amdgcn_mfma_f32_16x16x32_bf16(pf0, vf, o1, 0, 0, 0);
            vf = *(const short8*)&Vl[cur][vr1 * 64 + (((4 + t4) ^ (vr1 & 7)) * 8)];
            o1 = __builtin_amdgcn_mfma_f32_16x16x32_bf16(pf1, vf, o1, 0, 0, 0);
            vf = *(const short8*)&Vl[cur][vr2 * 64 + ((t4 ^ (vr2 & 7)) * 8)];
            o2 = __builtin_amdgcn_mfma_f32_16x16x32_bf16(pf0, vf, o2, 0, 0, 0);
            vf = *(const short8*)&Vl[cur][vr2 * 64 + (((4 + t4) ^ (vr2 & 7)) * 8)];
            o2 = __builtin_amdgcn_mfma_f32_16x16x32_bf16(pf1, vf, o2, 0, 0, 0);
            vf = *(const short8*)&Vl[cur][vr3 * 64 + ((t4 ^ (vr3 & 7)) * 8)];
            o3 = __builtin_amdgcn_mfma_f32_16x16x32_bf16(pf0, vf, o3, 0, 0, 0);
            vf = *(const short8*)&Vl[cur][vr3 * 64 + (((4 + t4) ^ (vr3 & 7)) * 8)];
            o3 = __builtin_amdgcn_mfma_f32_16x16x32_bf16(pf1, vf, o3, 0, 0, 0);
        }
        __builtin_amdgcn_s_setprio(0);

        asm volatile("s_waitcnt lgkmcnt(0)" ::: "memory");
        __builtin_amdgcn_s_barrier();
        __builtin_amdgcn_sched_barrier(0);
        if (jt + 2 < 9) stage(jt + 2, cur);
    }

    #pragma unroll
    for (int r = 0; r < 4; r++) {
        float s = lrow[r];
        s += __shfl_xor(s, 1);
        s += __shfl_xor(s, 2);
        s += __shfl_xor(s, 4);
        s += __shfl_xor(s, 8);
        int q = q0 + t4 * 4 + r;
        if (q < SEQ) {
            float inv = 1.f / s;
            short* ao = aob + ((size_t)(b * SEQ + q)) * DIM + h * 64 + c;
            ao[0]  = (short)f2bf(o0[r] * inv);
            ao[16] = (short)f2bf(o1[r] * inv);
            ao[32] = (short)f2bf(o2[r] * inv);
            ao[48] = (short)f2bf(o3[r] * inv);
        }
    }
}

// ---------------------------------------------------------------------------
// LayerNorm (input already contains residual sum): hb = LN(sum)*g + b
// ---------------------------------------------------------------------------
__global__ __launch_bounds__(256) void k_ln(short* __restrict__ hb,
                                            const short* __restrict__ sum,
                                            const float* __restrict__ g,
                                            const float* __restrict__ bta) {
    int row = blockIdx.x * 4 + (threadIdx.x >> 6);
    int l = threadIdx.x & 63;
    size_t base = (size_t)row * DIM + l * 8;
    short8 hv = *(const short8*)&sum[base];
    float a[8];
    float s1 = 0.f, s2 = 0.f;
    #pragma unroll
    for (int e = 0; e < 8; e++) {
        a[e] = bf2f(hv[e]);
        s1 += a[e];
        s2 += a[e] * a[e];
    }
    s1 = wred_sum(s1);
    s2 = wred_sum(s2);
    float mu = s1 * (1.f / 512.f);
    float rr = rsqrtf(s2 * (1.f / 512.f) - mu * mu + 1e-6f);
    float4 g0 = *(const float4*)&g[l * 8];
    float4 g1 = *(const float4*)&g[l * 8 + 4];
    float4 b0 = *(const float4*)&bta[l * 8];
    float4 b1 = *(const float4*)&bta[l * 8 + 4];
    unsigned o[4];
    o[0] = cvt_pk_bf16((a[0] - mu) * rr * g0.x + b0.x,
                       (a[1] - mu) * rr * g0.y + b0.y);
    o[1] = cvt_pk_bf16((a[2] - mu) * rr * g0.z + b0.z,
                       (a[3] - mu) * rr * g0.w + b0.w);
    o[2] = cvt_pk_bf16((a[4] - mu) * rr * g1.x + b1.x,
                       (a[5] - mu) * rr * g1.y + b1.y);
    o[3] = cvt_pk_bf16((a[6] - mu) * rr * g1.z + b1.z,
                       (a[7] - mu) * rr * g1.w + b1.w);
    *(uint4*)&hb[base] = make_uint4(o[0], o[1], o[2], o[3]);
}

// ---------------------------------------------------------------------------
// Head hidden: hid[b,o,j] = relu(x_cls[b,o,:] @ Wh[o] + bh[o,j])
// ---------------------------------------------------------------------------
__global__ __launch_bounds__(256) void k_hid(const short* __restrict__ hb,
                                             const float* __restrict__ Wh,
                                             const float* __restrict__ bh,
                                             float* __restrict__ hid) {
    int j = blockIdx.x * 256 + threadIdx.x;
    int o = blockIdx.y, b = blockIdx.z;
    const short* xr = hb + ((size_t)(b * SEQ + o)) * DIM;
    const float* wcol = Wh + (size_t)o * DIM * DIM + j;
    float acc = bh[o * DIM + j];
    #pragma unroll 8
    for (int d = 0; d < DIM; d++)
        acc = fmaf(bf2f(xr[d]), wcol[(size_t)d * DIM], acc);
    hid[((size_t)b * 8 + o) * DIM + j] = fmaxf(acc, 0.f);
}

// ---------------------------------------------------------------------------
__device__ __forceinline__ float softplus_f(float x) { return log1pf(expf(x)); }

__global__ __launch_bounds__(64) void k_var(const float* __restrict__ hid,
                                            const float* __restrict__ mu_wmu,
                                            const float* __restrict__ mu_wrho,
                                            const float* __restrict__ mu_bmu,
                                            const float* __restrict__ mu_brho,
                                            const float* __restrict__ lv_wmu,
                                            const float* __restrict__ lv_wrho,
                                            const float* __restrict__ lv_bmu,
                                            const float* __restrict__ lv_brho,
                                            const float* __restrict__ eps_mu_w,
                                            const float* __restrict__ eps_mu_b,
                                            const float* __restrict__ eps_lv_w,
                                            const float* __restrict__ eps_lv_b,
                                            float* __restrict__ out) {
    const float EPS = 1e-8f;
    int bo = blockIdx.x;
    int o = bo & 7;
    int l = threadIdx.x;
    float am = 0.f, al = 0.f;
    #pragma unroll
    for (int k = 0; k < 8; k++) {
        int d = k * 64 + l;
        int od = o * DIM + d;
        float hv = hid[(size_t)bo * DIM + d];
        am = fmaf(hv, mu_wmu[od] + (softplus_f(mu_wrho[od]) + EPS) * eps_mu_w[od], am);
        al = fmaf(hv, lv_wmu[od] + (softplus_f(lv_wrho[od]) + EPS) * eps_lv_w[od], al);
    }
    am = wred_sum(am);
    al = wred_sum(al);
    if (l == 0) {
        float mu = am + mu_bmu[o] + (softplus_f(mu_brho[o]) + EPS) * eps_mu_b[o];
        out[bo] = mu;
        float lvv = al + lv_bmu[o] + (softplus_f(lv_brho[o]) + EPS) * eps_lv_b[o];
        out[256 + bo] = logf(EPS + softplus_f(lvv));
    }
}

// ---------------------------------------------------------------------------
extern "C" void kernel_launch(void* const* d_in, const int* in_sizes, int n_in,
                              void* d_out, int out_size, void* d_ws, size_t ws_size,
                              hipStream_t stream) {
    const float* x      = (const float*)d_in[0];
    const float* W_in   = (const float*)d_in[1];
    const float* b_in   = (const float*)d_in[2];
    const float* cls    = (const float*)d_in[3];
    const float* Wqkv   = (const float*)d_in[4];
    const float* bqkv   = (const float*)d_in[5];
    const float* Wo     = (const float*)d_in[6];
    const float* bo     = (const float*)d_in[7];
    const float* ln1_g  = (const float*)d_in[8];
    const float* ln1_b  = (const float*)d_in[9];
    const float* Wm1    = (const float*)d_in[10];
    const float* bm1    = (const float*)d_in[11];
    const float* Wm2    = (const float*)d_in[12];
    const float* bm2    = (const float*)d_in[13];
    const float* ln2_g  = (const float*)d_in[14];
    const float* ln2_b  = (const float*)d_in[15];
    const float* Wh     = (const float*)d_in[16];
    const float* bh     = (const float*)d_in[17];
    const float* mu_wmu = (const float*)d_in[18];
    const float* mu_wrho= (const float*)d_in[19];
    const float* mu_bmu = (const float*)d_in[20];
    const float* mu_brho= (const float*)d_in[21];
    const float* lv_wmu = (const float*)d_in[22];
    const float* lv_wrho= (const float*)d_in[23];
    const float* lv_bmu = (const float*)d_in[24];
    const float* lv_brho= (const float*)d_in[25];
    const float* e_mu_w = (const float*)d_in[26];
    const float* e_mu_b = (const float*)d_in[27];
    const float* e_lv_w = (const float*)d_in[28];
    const float* e_lv_b = (const float*)d_in[29];
    float* out = (float*)d_out;

    char* p = (char*)d_ws;
    auto alloc = [&](size_t bytes) {
        char* r = p;
        p += (bytes + 255) & ~(size_t)255;
        return r;
    };
    const size_t qkv_bytes = (size_t)NROW * 1536 * 2;
    const size_t kbuf_bytes = (size_t)BATCH * NHEAD * SP * 64 * 2;
    const size_t attn_bytes = qkv_bytes + 2 * kbuf_bytes + 512;
    const size_t mid_bytes = (size_t)NROW * MLPD * 2;
    char*   U1    =          alloc(attn_bytes > mid_bytes ? attn_bytes : mid_bytes);
    short*  qkv   = (short*)U1;
    short*  kbuf  = (short*)(U1 + ((qkv_bytes + 255) & ~(size_t)255));
    short*  vtbuf = kbuf + kbuf_bytes / 2;
    short*  mid   = (short*)U1;
    short*  hb    = (short*) alloc((size_t)NROW * DIM * 2);
    short*  deltab= (short*) alloc((size_t)NROW * DIM * 2);
    short*  aob   = (short*) alloc((size_t)NROW * DIM * 2);
    short*  wqkvt = (short*) alloc((size_t)NLAYER * 1536 * 512 * 2);
    short*  wot   = (short*) alloc((size_t)NLAYER * 512 * 512 * 2);
    short*  wm1t  = (short*) alloc((size_t)NLAYER * 2048 * 512 * 2);
    short*  wm2t  = (short*) alloc((size_t)NLAYER * 512 * 2048 * 2);
    float2* ropet = (float2*)alloc((size_t)SEQ * NPAIR * 8);
    float*  hid   = (float*) alloc((size_t)256 * DIM * 4);

    k_wconv<<<dim3(24, 8, 4), 256, 0, stream>>>(Wqkv, wqkvt, 512, 1536);
    k_wconv<<<dim3(8, 8, 4),  256, 0, stream>>>(Wo,   wot,   512, 512);
    k_wconv<<<dim3(32, 8, 4), 256, 0, stream>>>(Wm1,  wm1t,  512, 2048);
    k_wconv<<<dim3(8, 32, 4), 256, 0, stream>>>(Wm2,  wm2t,  2048, 512);
    k_rope_tab<<<SEQ, NPAIR, 0, stream>>>(ropet);
    k_in_proj<<<NROW, 256, 0, stream>>>(x, W_in, b_in, cls, hb);

    const int RT = NROW / 128;   // 130
    for (int l = 0; l < NLAYER; l++) {
        k_gemm<32, false, false><<<RT * 12, 512, 0, stream>>>(
            hb, wqkvt + (size_t)l * 1536 * 512, bqkv + l * 1536, nullptr, qkv, 1536, 512);
        k_kvprep<<<BATCH * NHEAD * 9, 256, 0, stream>>>(qkv, ropet, kbuf, vtbuf);
        k_attn_mfma<<<9 * 256, 256, 0, stream>>>(qkv, kbuf, vtbuf, ropet, aob);
        k_gemm64<32, false, true><<<RT * 8, 256, 0, stream>>>(
            aob, wot + (size_t)l * 512 * 512, bo + l * 512, hb, deltab, 512, 512);
        k_ln<<<NROW / 4, 256, 0, stream>>>(hb, deltab, ln1_g + l * 512, ln1_b + l * 512);
        k_gemm<32, true, false><<<RT * 16, 512, 0, stream>>>(
            hb, wm1t + (size_t)l * 2048 * 512, bm1 + l * 2048, nullptr, mid, 2048, 512);
        k_gemm64<64, false, true><<<RT * 8, 256, 0, stream>>>(
            mid, wm2t + (size_t)l * 512 * 2048, bm2 + l * 512, hb, deltab, 512, 2048);
        k_ln<<<NROW / 4, 256, 0, stream>>>(hb, deltab, ln2_g + l * 512, ln2_b + l * 512);
    }

    k_hid<<<dim3(2, 8, 32), 256, 0, stream>>>(hb, Wh, bh, hid);
    k_var<<<256, 64, 0, stream>>>(hid, mu_wmu, mu_wrho, mu_bmu, mu_brho,
                                  lv_wmu, lv_wrho, lv_bmu, lv_brho,
                                  e_mu_w, e_mu_b, e_lv_w, e_lv_b, out);
}

// Round 10
// 1036.821 us; speedup vs baseline: 1.0599x; 1.0345x over previous
//
#include <hip/hip_runtime.h>
#include <cstdint>

// ---------------------------------------------------------------------------
// QRoPETRegressor: 4-layer transformer (B=32, S=520 w/ 8 cls, D=512, NH=8,
// HD=64, MLP=2048) + variational heads.
// R10: attention -> 8-wave blocks (QBLK=128, K/V staged once per 128 q-rows,
//      24 waves/CU).  GEMMs unchanged from R9.
// ---------------------------------------------------------------------------

#define BATCH   32
#define SEQ     520
#define SP      576
#define DIM     512
#define NHEAD   8
#define HDIM    64
#define MLPD    2048
#define NLAYER  4
#define NROW    (BATCH * SEQ)   // 16640
#define NPAIR   256

typedef __attribute__((ext_vector_type(4))) float  f32x4;
typedef __attribute__((ext_vector_type(8))) short  short8;

__device__ __forceinline__ unsigned short f2bf(float f) {
    unsigned u = __float_as_uint(f);
    unsigned r = (u + 0x7fffu + ((u >> 16) & 1u)) >> 16;
    return (unsigned short)r;
}
__device__ __forceinline__ float bf2f(short s) {
    return __uint_as_float(((unsigned)(unsigned short)s) << 16);
}
__device__ __forceinline__ unsigned cvt_pk_bf16(float lo, float hi) {
    unsigned r;
    asm("v_cvt_pk_bf16_f32 %0, %1, %2" : "=v"(r) : "v"(lo), "v"(hi));
    return r;
}
__device__ __forceinline__ float exp2_hw(float x) {
    float r;
    asm("v_exp_f32 %0, %1" : "=v"(r) : "v"(x));
    return r;
}
__device__ __forceinline__ float wred_sum(float v) {
    #pragma unroll
    for (int off = 32; off; off >>= 1) v += __shfl_xor(v, off);
    return v;
}

__device__ __forceinline__ void gload16(const void* g, void* l) {
    __builtin_amdgcn_global_load_lds(
        (const __attribute__((address_space(1))) unsigned int*)g,
        (__attribute__((address_space(3))) unsigned int*)l,
        16, 0, 0);
}

// ---------------------------------------------------------------------------
// Weight transpose-convert: src fp32 (K,N) -> dst bf16 (N,K)
// ---------------------------------------------------------------------------
__global__ __launch_bounds__(256) void k_wconv(const float* __restrict__ src,
                                               short* __restrict__ dst,
                                               int K, int N) {
    src += (size_t)blockIdx.z * K * N;
    dst += (size_t)blockIdx.z * K * N;
    int n0 = blockIdx.x * 64, k0 = blockIdx.y * 64;
    __shared__ float t[64][65];
    int tid = threadIdx.x;
    int r = tid >> 2, cq = (tid & 3) * 16;
    const float* sp = src + (size_t)(k0 + r) * N + n0 + cq;
    #pragma unroll
    for (int e = 0; e < 16; e += 4) {
        float4 v = *(const float4*)(sp + e);
        t[r][cq + e] = v.x; t[r][cq + e + 1] = v.y;
        t[r][cq + e + 2] = v.z; t[r][cq + e + 3] = v.w;
    }
    __syncthreads();
    int n = tid >> 2, kq = (tid & 3) * 16;
    short* dp = dst + (size_t)(n0 + n) * K + k0 + kq;
    unsigned o0[4], o1[4];
    #pragma unroll
    for (int e = 0; e < 4; e++)
        o0[e] = cvt_pk_bf16(t[kq + 2 * e][n], t[kq + 2 * e + 1][n]);
    #pragma unroll
    for (int e = 0; e < 4; e++)
        o1[e] = cvt_pk_bf16(t[kq + 8 + 2 * e][n], t[kq + 9 + 2 * e][n]);
    *(uint4*)dp = make_uint4(o0[0], o0[1], o0[2], o0[3]);
    *(uint4*)(dp + 8) = make_uint4(o1[0], o1[1], o1[2], o1[3]);
}

// ---------------------------------------------------------------------------
__global__ void k_rope_tab(float2* __restrict__ tab) {
    int s = blockIdx.x, i = threadIdx.x;
    float fr = powf(10000.f, -2.f * (float)i / 512.f);
    float th = (float)s * fr;
    float sn, cn;
    sincosf(th, &sn, &cn);
    tab[s * NPAIR + i] = make_float2(cn, sn);
}

// ---------------------------------------------------------------------------
// Input proj + cls concat -> bf16 h
// ---------------------------------------------------------------------------
__global__ __launch_bounds__(256) void k_in_proj(const float* __restrict__ x,
                                                 const float* __restrict__ Wi,
                                                 const float* __restrict__ bi,
                                                 const float* __restrict__ cls,
                                                 short* __restrict__ hb) {
    int row = blockIdx.x;
    int b = row / SEQ, s = row % SEQ;
    bool is_cls = s < 8;
    float xr[16];
    if (!is_cls) {
        const float* xp = x + (size_t)(b * 512 + (s - 8)) * 16;
        #pragma unroll
        for (int f = 0; f < 16; f++) xr[f] = xp[f];
    }
    for (int c = threadIdx.x; c < DIM; c += 256) {
        float v;
        if (is_cls) {
            v = cls[s * DIM + c];
        } else {
            v = bi[c];
            #pragma unroll
            for (int f = 0; f < 16; f++) v = fmaf(xr[f], Wi[f * DIM + c], v);
        }
        hb[(size_t)row * DIM + c] = (short)f2bf(v);
    }
}

// ---------------------------------------------------------------------------
// GEMM (128x128 tile, 8 waves): for N >= 1024 shapes (qkv, MLP1).
// Counted-vmcnt depth-2, XOR-swizzle, XCD-chunked tile order.
// ---------------------------------------------------------------------------
template <int BK, bool RELU, bool ADDRES>
__global__ __launch_bounds__(512) void k_gemm(const short* __restrict__ A,
                                              const short* __restrict__ Bt,
                                              const float* __restrict__ bias,
                                              const short* __restrict__ Res,
                                              short* __restrict__ Cout,
                                              int N, int K) {
    constexpr int NB  = BK / 8;
    constexpr int MSK = NB - 1;
    constexpr int RPW = 64 / NB;          // rows per gload16
    constexpr int GPM = 128 / (8 * RPW);  // loads per matrix per wave
    constexpr int NLD = 2 * GPM;
    __shared__ __align__(16) short As[2][128 * BK];
    __shared__ __align__(16) short Bs[2][128 * BK];
    const int tid = threadIdx.x;
    const int w = tid >> 6, l = tid & 63;

    const int chunk = gridDim.x >> 3;
    const int t = (blockIdx.x & 7) * chunk + (blockIdx.x >> 3);
    const int C = N >> 7;
    const int brow = (t / C) * 128, bcol = (t % C) * 128;

    const int srow = l / NB;
    const int sblk = l & MSK;
    const int soff = ((sblk ^ (srow & MSK)) * 8);
    const int fr = l & 15, t4 = l >> 4;
    const int wr = (w >> 2) * 64;
    const int wc = (w & 3) * 32;

    const short* Ab = A  + (size_t)(brow + w * RPW + srow) * K + soff;
    const short* Bb = Bt + (size_t)(bcol + w * RPW + srow) * K + soff;

    f32x4 acc[4][2];
    #pragma unroll
    for (int m = 0; m < 4; m++)
        #pragma unroll
        for (int n = 0; n < 2; n++) acc[m][n] = (f32x4){0.f, 0.f, 0.f, 0.f};

    auto stage = [&](int ko, int pb) {
        #pragma unroll
        for (int i = 0; i < GPM; i++)
            gload16(Ab + (size_t)(i * 8 * RPW) * K + ko,
                    &As[pb][(i * 8 * RPW + w * RPW) * BK]);
        #pragma unroll
        for (int i = 0; i < GPM; i++)
            gload16(Bb + (size_t)(i * 8 * RPW) * K + ko,
                    &Bs[pb][(i * 8 * RPW + w * RPW) * BK]);
    };

    const int nk = K / BK;
    stage(0, 0);
    stage(BK, 1);

    for (int kt = 0; kt < nk; ++kt) {
        const int cur = kt & 1;
        if (kt + 1 < nk) {
            if constexpr (NLD == 4) asm volatile("s_waitcnt vmcnt(4)" ::: "memory");
            else                    asm volatile("s_waitcnt vmcnt(2)" ::: "memory");
        } else {
            asm volatile("s_waitcnt vmcnt(0)" ::: "memory");
        }
        __builtin_amdgcn_s_barrier();
        __builtin_amdgcn_sched_barrier(0);

        short8 af[4][BK / 32], bf[2][BK / 32];
        #pragma unroll
        for (int m = 0; m < 4; m++) {
            int r = wr + m * 16 + fr;
            #pragma unroll
            for (int kk = 0; kk < BK / 32; kk++)
                af[m][kk] = *(const short8*)
                    &As[cur][r * BK + (((kk * 4 + t4) ^ (r & MSK)) * 8)];
        }
        #pragma unroll
        for (int n = 0; n < 2; n++) {
            int r = wc + n * 16 + fr;
            #pragma unroll
            for (int kk = 0; kk < BK / 32; kk++)
                bf[n][kk] = *(const short8*)
                    &Bs[cur][r * BK + (((kk * 4 + t4) ^ (r & MSK)) * 8)];
        }
        asm volatile("s_waitcnt lgkmcnt(0)" ::: "memory");
        __builtin_amdgcn_s_barrier();
        __builtin_amdgcn_sched_barrier(0);
        if (kt + 2 < nk) stage((kt + 2) * BK, cur);

        __builtin_amdgcn_s_setprio(1);
        #pragma unroll
        for (int kk = 0; kk < BK / 32; kk++)
            #pragma unroll
            for (int m = 0; m < 4; m++)
                #pragma unroll
                for (int n = 0; n < 2; n++)
                    acc[m][n] = __builtin_amdgcn_mfma_f32_16x16x32_bf16(
                        af[m][kk], bf[n][kk], acc[m][n], 0, 0, 0);
        __builtin_amdgcn_s_setprio(0);
    }

    const int r0 = (l >> 4) * 4, c0 = l & 15;
    #pragma unroll
    for (int m = 0; m < 4; m++) {
        #pragma unroll
        for (int n = 0; n < 2; n++) {
            int col = bcol + wc + n * 16 + c0;
            float bv = bias[col];
            #pragma unroll
            for (int q = 0; q < 4; q++) {
                int row = brow + wr + m * 16 + r0 + q;
                float v = acc[m][n][q] + bv;
                if (ADDRES) v += bf2f(Res[(size_t)row * N + col]);
                if (RELU) v = fmaxf(v, 0.f);
                Cout[(size_t)row * N + col] = (short)f2bf(v);
            }
        }
    }
}

// ---------------------------------------------------------------------------
// GEMM (128x64 tile, 4 waves): for N=512 shapes (Wo, MLP2).
// ---------------------------------------------------------------------------
template <int BK, bool RELU, bool ADDRES>
__global__ __launch_bounds__(256) void k_gemm64(const short* __restrict__ A,
                                                const short* __restrict__ Bt,
                                                const float* __restrict__ bias,
                                                const short* __restrict__ Res,
                                                short* __restrict__ Cout,
                                                int N, int K) {
    constexpr int NB  = BK / 8;
    constexpr int MSK = NB - 1;
    constexpr int RPL = 512 / BK;
    constexpr int ALW = 128 / (4 * RPL);
    constexpr int BLW = 64 / (4 * RPL);
    constexpr int NLD = ALW + BLW;
    __shared__ __align__(16) short As[2][128 * BK];
    __shared__ __align__(16) short Bs[2][64 * BK];
    const int tid = threadIdx.x;
    const int w = tid >> 6, l = tid & 63;

    const int chunk = gridDim.x >> 3;
    const int t = (blockIdx.x & 7) * chunk + (blockIdx.x >> 3);
    const int C = N >> 6;
    const int brow = (t / C) * 128, bcol = (t % C) * 64;

    const int srow = l / NB;
    const int sblk = l & MSK;
    const int soff = ((sblk ^ (srow & MSK)) * 8);
    const int fr = l & 15, t4 = l >> 4;
    const int wr = (w >> 1) * 64;
    const int wc = (w & 1) * 32;

    f32x4 acc[4][2];
    #pragma unroll
    for (int m = 0; m < 4; m++)
        #pragma unroll
        for (int n = 0; n < 2; n++) acc[m][n] = (f32x4){0.f, 0.f, 0.f, 0.f};

    auto stage = [&](int ko, int pb) {
        #pragma unroll
        for (int i = 0; i < ALW; i++)
            gload16(A + (size_t)(brow + (w * ALW + i) * RPL + srow) * K + ko + soff,
                    &As[pb][((w * ALW + i) * RPL) * BK]);
        #pragma unroll
        for (int i = 0; i < BLW; i++)
            gload16(Bt + (size_t)(bcol + (w * BLW + i) * RPL + srow) * K + ko + soff,
                    &Bs[pb][((w * BLW + i) * RPL) * BK]);
    };

    const int nk = K / BK;
    stage(0, 0);
    stage(BK, 1);

    for (int kt = 0; kt < nk; ++kt) {
        const int cur = kt & 1;
        if (kt + 1 < nk) {
            if constexpr (NLD == 3) asm volatile("s_waitcnt vmcnt(3)" ::: "memory");
            else                    asm volatile("s_waitcnt vmcnt(6)" ::: "memory");
        } else {
            asm volatile("s_waitcnt vmcnt(0)" ::: "memory");
        }
        __builtin_amdgcn_s_barrier();
        __builtin_amdgcn_sched_barrier(0);

        short8 af[4][BK / 32], bf[2][BK / 32];
        #pragma unroll
        for (int m = 0; m < 4; m++) {
            int r = wr + m * 16 + fr;
            #pragma unroll
            for (int kk = 0; kk < BK / 32; kk++)
                af[m][kk] = *(const short8*)
                    &As[cur][r * BK + (((kk * 4 + t4) ^ (r & MSK)) * 8)];
        }
        #pragma unroll
        for (int n = 0; n < 2; n++) {
            int r = wc + n * 16 + fr;
            #pragma unroll
            for (int kk = 0; kk < BK / 32; kk++)
                bf[n][kk] = *(const short8*)
                    &Bs[cur][r * BK + (((kk * 4 + t4) ^ (r & MSK)) * 8)];
        }
        asm volatile("s_waitcnt lgkmcnt(0)" ::: "memory");
        __builtin_amdgcn_s_barrier();
        __builtin_amdgcn_sched_barrier(0);
        if (kt + 2 < nk) stage((kt + 2) * BK, cur);

        __builtin_amdgcn_s_setprio(1);
        #pragma unroll
        for (int kk = 0; kk < BK / 32; kk++)
            #pragma unroll
            for (int m = 0; m < 4; m++)
                #pragma unroll
                for (int n = 0; n < 2; n++)
                    acc[m][n] = __builtin_amdgcn_mfma_f32_16x16x32_bf16(
                        af[m][kk], bf[n][kk], acc[m][n], 0, 0, 0);
        __builtin_amdgcn_s_setprio(0);
    }

    const int r0 = (l >> 4) * 4, c0 = l & 15;
    #pragma unroll
    for (int m = 0; m < 4; m++) {
        #pragma unroll
        for (int n = 0; n < 2; n++) {
            int col = bcol + wc + n * 16 + c0;
            float bv = bias[col];
            #pragma unroll
            for (int q = 0; q < 4; q++) {
                int row = brow + wr + m * 16 + r0 + q;
                float v = acc[m][n][q] + bv;
                if (ADDRES) v += bf2f(Res[(size_t)row * N + col]);
                if (RELU) v = fmaxf(v, 0.f);
                Cout[(size_t)row * N + col] = (short)f2bf(v);
            }
        }
    }
}

// ---------------------------------------------------------------------------
// K/V prep: rope K -> kbuf[bh][SP][64]; transpose V -> vtbuf[bh][64][SP].
// ---------------------------------------------------------------------------
__global__ __launch_bounds__(256) void k_kvprep(const short* __restrict__ qkv,
                                                const float2* __restrict__ tab,
                                                short* __restrict__ kbuf,
                                                short* __restrict__ vtbuf) {
    int bx = blockIdx.x;
    int jt = bx % 9, bh = bx / 9, b = bh >> 3, h = bh & 7;
    int tid = threadIdx.x;
    int row = tid >> 2, ch = tid & 3;
    int s = jt * 64 + row;
    bool valid = s < SEQ;
    size_t g = (size_t)(b * SEQ + (valid ? s : 0)) * 1536;

    short8 ok0 = (short8)0, ok1 = (short8)0;
    if (valid) {
        short8 k0 = *(const short8*)(qkv + g + 512 + h * 64 + ch * 16);
        short8 k1 = *(const short8*)(qkv + g + 512 + h * 64 + ch * 16 + 8);
        unsigned* u0 = (unsigned*)&ok0;
        unsigned* u1 = (unsigned*)&ok1;
        #pragma unroll
        for (int pp = 0; pp < 4; pp++) {
            float2 cs = tab[s * NPAIR + h * 32 + ch * 8 + pp];
            float x1 = bf2f(k0[2 * pp]), x2 = bf2f(k0[2 * pp + 1]);
            u0[pp] = cvt_pk_bf16(x1 * cs.x - x2 * cs.y, x1 * cs.y + x2 * cs.x);
            cs = tab[s * NPAIR + h * 32 + ch * 8 + 4 + pp];
            x1 = bf2f(k1[2 * pp]); x2 = bf2f(k1[2 * pp + 1]);
            u1[pp] = cvt_pk_bf16(x1 * cs.x - x2 * cs.y, x1 * cs.y + x2 * cs.x);
        }
    }
    short* kd = kbuf + ((size_t)bh * SP + jt * 64 + row) * 64 + ch * 16;
    *(short8*)kd = ok0;
    *(short8*)(kd + 8) = ok1;

    __shared__ short vt[64][72];
    short8 v0 = (short8)0, v1 = (short8)0;
    if (valid) {
        v0 = *(const short8*)(qkv + g + 1024 + h * 64 + ch * 16);
        v1 = *(const short8*)(qkv + g + 1024 + h * 64 + ch * 16 + 8);
    }
    *(short8*)&vt[row][ch * 16] = v0;
    *(short8*)&vt[row][ch * 16 + 8] = v1;
    __syncthreads();
    int d = row;
    short8 w0, w1;
    #pragma unroll
    for (int e = 0; e < 8; e++) w0[e] = vt[ch * 16 + e][d];
    #pragma unroll
    for (int e = 0; e < 8; e++) w1[e] = vt[ch * 16 + 8 + e][d];
    short* vd = vtbuf + ((size_t)bh * 64 + d) * SP + jt * 64 + ch * 16;
    *(short8*)vd = w0;
    *(short8*)(vd + 8) = w1;
}

// ---------------------------------------------------------------------------
// MFMA flash attention: 8 waves, QBLK=128 (wave w owns q rows qt*128+w*16..).
// K/V staged ONCE per 128 q-rows; counted-vmcnt depth-2; rope fused on Q;
// log2-domain softmax with defer-max + lazy sum.
// grid: bx = qt*256 + bh,  qt in 0..4
// ---------------------------------------------------------------------------
__global__ __launch_bounds__(512) void k_attn_mfma(const short* __restrict__ qkv,
                                                   const short* __restrict__ kbuf,
                                                   const short* __restrict__ vtbuf,
                                                   const float2* __restrict__ tab,
                                                   short* __restrict__ aob) {
    __shared__ __align__(16) short Kl[2][64 * 64];
    __shared__ __align__(16) short Vl[2][64 * 64];
    __shared__ __align__(16) short sP[8][16][72];
    const int tid = threadIdx.x;
    const int w = tid >> 6, l = tid & 63;
    const int c = l & 15, t4 = l >> 4;
    int bx = blockIdx.x;
    int qt = bx >> 8, bh = bx & 255, b = bh >> 3, h = bh & 7;

    // ---- Q fragments, rope fused, scaled by 0.125*log2(e) (exp2 domain) ----
    const float QSC = 0.125f * 1.44269504f;
    int q0 = qt * 128 + w * 16;
    int qrow = q0 + c;
    int qr = qrow < SEQ ? qrow : SEQ - 1;
    size_t gq = (size_t)(b * SEQ + qr) * 1536 + h * 64;
    short8 qf0 = *(const short8*)(qkv + gq + t4 * 8);
    short8 qf1 = *(const short8*)(qkv + gq + 32 + t4 * 8);
    {
        const float2* tq = tab + (size_t)qr * NPAIR + h * 32;
        unsigned* u0 = (unsigned*)&qf0;
        unsigned* u1 = (unsigned*)&qf1;
        #pragma unroll
        for (int pp = 0; pp < 4; pp++) {
            float2 cs = tq[t4 * 4 + pp];
            float x1 = bf2f(qf0[2 * pp]), x2 = bf2f(qf0[2 * pp + 1]);
            u0[pp] = cvt_pk_bf16((x1 * cs.x - x2 * cs.y) * QSC,
                                 (x1 * cs.y + x2 * cs.x) * QSC);
            cs = tq[16 + t4 * 4 + pp];
            x1 = bf2f(qf1[2 * pp]); x2 = bf2f(qf1[2 * pp + 1]);
            u1[pp] = cvt_pk_bf16((x1 * cs.x - x2 * cs.y) * QSC,
                                 (x1 * cs.y + x2 * cs.x) * QSC);
        }
    }

    f32x4 o0 = {0,0,0,0}, o1 = {0,0,0,0}, o2 = {0,0,0,0}, o3 = {0,0,0,0};
    float mrow[4] = {-1e30f, -1e30f, -1e30f, -1e30f};
    float lrow[4] = {0.f, 0.f, 0.f, 0.f};

    const short* kb = kbuf + (size_t)bh * SP * 64;
    const short* vb = vtbuf + (size_t)bh * 64 * SP;
    // 8 waves stage 64 K-rows + 64 V-rows: wave w covers rows w*8..w*8+8
    const int r1 = w * 8 + (l >> 3);
    const int blk = l & 7;

    auto stage = [&](int jt, int pb) {
        gload16(kb + ((size_t)(jt * 64 + r1)) * 64 + ((blk ^ (r1 & 7)) * 8),
                &Kl[pb][(w * 8) * 64]);
        gload16(vb + (size_t)r1 * SP + jt * 64 + ((blk ^ (r1 & 7)) * 8),
                &Vl[pb][(w * 8) * 64]);
    };

    stage(0, 0);
    stage(1, 1);

    for (int jt = 0; jt < 9; jt++) {
        const int cur = jt & 1;
        if (jt + 1 < 9) asm volatile("s_waitcnt vmcnt(2)" ::: "memory");
        else            asm volatile("s_waitcnt vmcnt(0)" ::: "memory");
        __builtin_amdgcn_s_barrier();
        __builtin_amdgcn_sched_barrier(0);

        // ---- QK^T (scores in log2 domain)
        f32x4 s0 = {0,0,0,0}, s1 = {0,0,0,0}, s2 = {0,0,0,0}, s3 = {0,0,0,0};
        __builtin_amdgcn_s_setprio(1);
        {
            int kr0 = c, kr1 = 16 + c, kr2 = 32 + c, kr3 = 48 + c;
            short8 kf;
            kf = *(const short8*)&Kl[cur][kr0 * 64 + ((t4 ^ (kr0 & 7)) * 8)];
            s0 = __builtin_amdgcn_mfma_f32_16x16x32_bf16(qf0, kf, s0, 0, 0, 0);
            kf = *(const short8*)&Kl[cur][kr0 * 64 + (((4 + t4) ^ (kr0 & 7)) * 8)];
            s0 = __builtin_amdgcn_mfma_f32_16x16x32_bf16(qf1, kf, s0, 0, 0, 0);
            kf = *(const short8*)&Kl[cur][kr1 * 64 + ((t4 ^ (kr1 & 7)) * 8)];
            s1 = __builtin_amdgcn_mfma_f32_16x16x32_bf16(qf0, kf, s1, 0, 0, 0);
            kf = *(const short8*)&Kl[cur][kr1 * 64 + (((4 + t4) ^ (kr1 & 7)) * 8)];
            s1 = __builtin_amdgcn_mfma_f32_16x16x32_bf16(qf1, kf, s1, 0, 0, 0);
            kf = *(const short8*)&Kl[cur][kr2 * 64 + ((t4 ^ (kr2 & 7)) * 8)];
            s2 = __builtin_amdgcn_mfma_f32_16x16x32_bf16(qf0, kf, s2, 0, 0, 0);
            kf = *(const short8*)&Kl[cur][kr2 * 64 + (((4 + t4) ^ (kr2 & 7)) * 8)];
            s2 = __builtin_amdgcn_mfma_f32_16x16x32_bf16(qf1, kf, s2, 0, 0, 0);
            kf = *(const short8*)&Kl[cur][kr3 * 64 + ((t4 ^ (kr3 & 7)) * 8)];
            s3 = __builtin_amdgcn_mfma_f32_16x16x32_bf16(qf0, kf, s3, 0, 0, 0);
            kf = *(const short8*)&Kl[cur][kr3 * 64 + (((4 + t4) ^ (kr3 & 7)) * 8)];
            s3 = __builtin_amdgcn_mfma_f32_16x16x32_bf16(qf1, kf, s3, 0, 0, 0);
        }
        __builtin_amdgcn_s_setprio(0);

        if (jt == 8) {
            #pragma unroll
            for (int r = 0; r < 4; r++) {
                if (c >= 8) s0[r] = -1e30f;
                s1[r] = -1e30f; s2[r] = -1e30f; s3[r] = -1e30f;
            }
        }

        // ---- online softmax: defer-max (THR=8 in log2 domain), lazy sum
        #pragma unroll
        for (int r = 0; r < 4; r++) {
            float pmax = fmaxf(fmaxf(s0[r], s1[r]), fmaxf(s2[r], s3[r]));
            if (!__all(pmax <= mrow[r] + 8.f)) {
                float mx = pmax;
                mx = fmaxf(mx, __shfl_xor(mx, 1));
                mx = fmaxf(mx, __shfl_xor(mx, 2));
                mx = fmaxf(mx, __shfl_xor(mx, 4));
                mx = fmaxf(mx, __shfl_xor(mx, 8));
                if (mx > mrow[r]) {
                    float sc = exp2_hw(mrow[r] - mx);
                    mrow[r] = mx;
                    lrow[r] *= sc;
                    o0[r] *= sc; o1[r] *= sc; o2[r] *= sc; o3[r] *= sc;
                }
            }
            float p0 = exp2_hw(s0[r] - mrow[r]);
            float p1 = exp2_hw(s1[r] - mrow[r]);
            float p2 = exp2_hw(s2[r] - mrow[r]);
            float p3 = exp2_hw(s3[r] - mrow[r]);
            lrow[r] += (p0 + p1) + (p2 + p3);
            unsigned pk01 = cvt_pk_bf16(p0, p1);
            unsigned pk23 = cvt_pk_bf16(p2, p3);
            int q = t4 * 4 + r;
            sP[w][q][c]      = (short)(pk01 & 0xffff);
            sP[w][q][16 + c] = (short)(pk01 >> 16);
            sP[w][q][32 + c] = (short)(pk23 & 0xffff);
            sP[w][q][48 + c] = (short)(pk23 >> 16);
        }

        // ---- PV
        __builtin_amdgcn_s_setprio(1);
        {
            short8 pf0 = *(const short8*)&sP[w][c][t4 * 8];
            short8 pf1 = *(const short8*)&sP[w][c][32 + t4 * 8];
            int vr0 = c, vr1 = 16 + c, vr2 = 32 + c, vr3 = 48 + c;
            short8 vf;
            vf = *(const short8*)&Vl[cur][vr0 * 64 + ((t4 ^ (vr0 & 7)) * 8)];
            o0 = __builtin_amdgcn_mfma_f32_16x16x32_bf16(pf0, vf, o0, 0, 0, 0);
            vf = *(const short8*)&Vl[cur][vr0 * 64 + (((4 + t4) ^ (vr0 & 7)) * 8)];
            o0 = __builtin_amdgcn_mfma_f32_16x16x32_bf16(pf1, vf, o0, 0, 0, 0);
            vf = *(const short8*)&Vl[cur][vr1 * 64 + ((t4 ^ (vr1 & 7)) * 8)];
            o1 = __builtin_amdgcn_mfma_f32_16x16x32_bf16(pf0, vf, o1, 0, 0, 0);
            vf = *(const short8*)&Vl[cur][vr1 * 64 + (((4 + t4) ^ (vr1 & 7)) * 8)];
            o1 = __builtin_amdgcn_mfma_f32_16x16x32_bf16(pf1, vf, o1, 0, 0, 0);
            vf = *(const short8*)&Vl[cur][vr2 * 64 + ((t4 ^ (vr2 & 7)) * 8)];
            o2 = __builtin_amdgcn_mfma_f32_16x16x32_bf16(pf0, vf, o2, 0, 0, 0);
            vf = *(const short8*)&Vl[cur][vr2 * 64 + (((4 + t4) ^ (vr2 & 7)) * 8)];
            o2 = __builtin_amdgcn_mfma_f32_16x16x32_bf16(pf1, vf, o2, 0, 0, 0);
            vf = *(const short8*)&Vl[cur][vr3 * 64 + ((t4 ^ (vr3 & 7)) * 8)];
            o3 = __builtin_amdgcn_mfma_f32_16x16x32_bf16(pf0, vf, o3, 0, 0, 0);
            vf = *(const short8*)&Vl[cur][vr3 * 64 + (((4 + t4) ^ (vr3 & 7)) * 8)];
            o3 = __builtin_amdgcn_mfma_f32_16x16x32_bf16(pf1, vf, o3, 0, 0, 0);
        }
        __builtin_amdgcn_s_setprio(0);

        asm volatile("s_waitcnt lgkmcnt(0)" ::: "memory");
        __builtin_amdgcn_s_barrier();
        __builtin_amdgcn_sched_barrier(0);
        if (jt + 2 < 9) stage(jt + 2, cur);
    }

    // ---- epilogue: one sum-reduce per row, normalize, store
    #pragma unroll
    for (int r = 0; r < 4; r++) {
        float s = lrow[r];
        s += __shfl_xor(s, 1);
        s += __shfl_xor(s, 2);
        s += __shfl_xor(s, 4);
        s += __shfl_xor(s, 8);
        int q = q0 + t4 * 4 + r;
        if (q < SEQ) {
            float inv = 1.f / s;
            short* ao = aob + ((size_t)(b * SEQ + q)) * DIM + h * 64 + c;
            ao[0]  = (short)f2bf(o0[r] * inv);
            ao[16] = (short)f2bf(o1[r] * inv);
            ao[32] = (short)f2bf(o2[r] * inv);
            ao[48] = (short)f2bf(o3[r] * inv);
        }
    }
}

// ---------------------------------------------------------------------------
// LayerNorm (input already contains residual sum): hb = LN(sum)*g + b
// ---------------------------------------------------------------------------
__global__ __launch_bounds__(256) void k_ln(short* __restrict__ hb,
                                            const short* __restrict__ sum,
                                            const float* __restrict__ g,
                                            const float* __restrict__ bta) {
    int row = blockIdx.x * 4 + (threadIdx.x >> 6);
    int l = threadIdx.x & 63;
    size_t base = (size_t)row * DIM + l * 8;
    short8 hv = *(const short8*)&sum[base];
    float a[8];
    float s1 = 0.f, s2 = 0.f;
    #pragma unroll
    for (int e = 0; e < 8; e++) {
        a[e] = bf2f(hv[e]);
        s1 += a[e];
        s2 += a[e] * a[e];
    }
    s1 = wred_sum(s1);
    s2 = wred_sum(s2);
    float mu = s1 * (1.f / 512.f);
    float rr = rsqrtf(s2 * (1.f / 512.f) - mu * mu + 1e-6f);
    float4 g0 = *(const float4*)&g[l * 8];
    float4 g1 = *(const float4*)&g[l * 8 + 4];
    float4 b0 = *(const float4*)&bta[l * 8];
    float4 b1 = *(const float4*)&bta[l * 8 + 4];
    unsigned o[4];
    o[0] = cvt_pk_bf16((a[0] - mu) * rr * g0.x + b0.x,
                       (a[1] - mu) * rr * g0.y + b0.y);
    o[1] = cvt_pk_bf16((a[2] - mu) * rr * g0.z + b0.z,
                       (a[3] - mu) * rr * g0.w + b0.w);
    o[2] = cvt_pk_bf16((a[4] - mu) * rr * g1.x + b1.x,
                       (a[5] - mu) * rr * g1.y + b1.y);
    o[3] = cvt_pk_bf16((a[6] - mu) * rr * g1.z + b1.z,
                       (a[7] - mu) * rr * g1.w + b1.w);
    *(uint4*)&hb[base] = make_uint4(o[0], o[1], o[2], o[3]);
}

// ---------------------------------------------------------------------------
// Head hidden: hid[b,o,j] = relu(x_cls[b,o,:] @ Wh[o] + bh[o,j])
// ---------------------------------------------------------------------------
__global__ __launch_bounds__(256) void k_hid(const short* __restrict__ hb,
                                             const float* __restrict__ Wh,
                                             const float* __restrict__ bh,
                                             float* __restrict__ hid) {
    int j = blockIdx.x * 256 + threadIdx.x;
    int o = blockIdx.y, b = blockIdx.z;
    const short* xr = hb + ((size_t)(b * SEQ + o)) * DIM;
    const float* wcol = Wh + (size_t)o * DIM * DIM + j;
    float acc = bh[o * DIM + j];
    #pragma unroll 8
    for (int d = 0; d < DIM; d++)
        acc = fmaf(bf2f(xr[d]), wcol[(size_t)d * DIM], acc);
    hid[((size_t)b * 8 + o) * DIM + j] = fmaxf(acc, 0.f);
}

// ---------------------------------------------------------------------------
__device__ __forceinline__ float softplus_f(float x) { return log1pf(expf(x)); }

__global__ __launch_bounds__(64) void k_var(const float* __restrict__ hid,
                                            const float* __restrict__ mu_wmu,
                                            const float* __restrict__ mu_wrho,
                                            const float* __restrict__ mu_bmu,
                                            const float* __restrict__ mu_brho,
                                            const float* __restrict__ lv_wmu,
                                            const float* __restrict__ lv_wrho,
                                            const float* __restrict__ lv_bmu,
                                            const float* __restrict__ lv_brho,
                                            const float* __restrict__ eps_mu_w,
                                            const float* __restrict__ eps_mu_b,
                                            const float* __restrict__ eps_lv_w,
                                            const float* __restrict__ eps_lv_b,
                                            float* __restrict__ out) {
    const float EPS = 1e-8f;
    int bo = blockIdx.x;
    int o = bo & 7;
    int l = threadIdx.x;
    float am = 0.f, al = 0.f;
    #pragma unroll
    for (int k = 0; k < 8; k++) {
        int d = k * 64 + l;
        int od = o * DIM + d;
        float hv = hid[(size_t)bo * DIM + d];
        am = fmaf(hv, mu_wmu[od] + (softplus_f(mu_wrho[od]) + EPS) * eps_mu_w[od], am);
        al = fmaf(hv, lv_wmu[od] + (softplus_f(lv_wrho[od]) + EPS) * eps_lv_w[od], al);
    }
    am = wred_sum(am);
    al = wred_sum(al);
    if (l == 0) {
        float mu = am + mu_bmu[o] + (softplus_f(mu_brho[o]) + EPS) * eps_mu_b[o];
        out[bo] = mu;
        float lvv = al + lv_bmu[o] + (softplus_f(lv_brho[o]) + EPS) * eps_lv_b[o];
        out[256 + bo] = logf(EPS + softplus_f(lvv));
    }
}

// ---------------------------------------------------------------------------
extern "C" void kernel_launch(void* const* d_in, const int* in_sizes, int n_in,
                              void* d_out, int out_size, void* d_ws, size_t ws_size,
                              hipStream_t stream) {
    const float* x      = (const float*)d_in[0];
    const float* W_in   = (const float*)d_in[1];
    const float* b_in   = (const float*)d_in[2];
    const float* cls    = (const float*)d_in[3];
    const float* Wqkv   = (const float*)d_in[4];
    const float* bqkv   = (const float*)d_in[5];
    const float* Wo     = (const float*)d_in[6];
    const float* bo     = (const float*)d_in[7];
    const float* ln1_g  = (const float*)d_in[8];
    const float* ln1_b  = (const float*)d_in[9];
    const float* Wm1    = (const float*)d_in[10];
    const float* bm1    = (const float*)d_in[11];
    const float* Wm2    = (const float*)d_in[12];
    const float* bm2    = (const float*)d_in[13];
    const float* ln2_g  = (const float*)d_in[14];
    const float* ln2_b  = (const float*)d_in[15];
    const float* Wh     = (const float*)d_in[16];
    const float* bh     = (const float*)d_in[17];
    const float* mu_wmu = (const float*)d_in[18];
    const float* mu_wrho= (const float*)d_in[19];
    const float* mu_bmu = (const float*)d_in[20];
    const float* mu_brho= (const float*)d_in[21];
    const float* lv_wmu = (const float*)d_in[22];
    const float* lv_wrho= (const float*)d_in[23];
    const float* lv_bmu = (const float*)d_in[24];
    const float* lv_brho= (const float*)d_in[25];
    const float* e_mu_w = (const float*)d_in[26];
    const float* e_mu_b = (const float*)d_in[27];
    const float* e_lv_w = (const float*)d_in[28];
    const float* e_lv_b = (const float*)d_in[29];
    float* out = (float*)d_out;

    char* p = (char*)d_ws;
    auto alloc = [&](size_t bytes) {
        char* r = p;
        p += (bytes + 255) & ~(size_t)255;
        return r;
    };
    const size_t qkv_bytes = (size_t)NROW * 1536 * 2;
    const size_t kbuf_bytes = (size_t)BATCH * NHEAD * SP * 64 * 2;
    const size_t attn_bytes = qkv_bytes + 2 * kbuf_bytes + 512;
    const size_t mid_bytes = (size_t)NROW * MLPD * 2;
    char*   U1    =          alloc(attn_bytes > mid_bytes ? attn_bytes : mid_bytes);
    short*  qkv   = (short*)U1;
    short*  kbuf  = (short*)(U1 + ((qkv_bytes + 255) & ~(size_t)255));
    short*  vtbuf = kbuf + kbuf_bytes / 2;
    short*  mid   = (short*)U1;
    short*  hb    = (short*) alloc((size_t)NROW * DIM * 2);
    short*  deltab= (short*) alloc((size_t)NROW * DIM * 2);
    short*  aob   = (short*) alloc((size_t)NROW * DIM * 2);
    short*  wqkvt = (short*) alloc((size_t)NLAYER * 1536 * 512 * 2);
    short*  wot   = (short*) alloc((size_t)NLAYER * 512 * 512 * 2);
    short*  wm1t  = (short*) alloc((size_t)NLAYER * 2048 * 512 * 2);
    short*  wm2t  = (short*) alloc((size_t)NLAYER * 512 * 2048 * 2);
    float2* ropet = (float2*)alloc((size_t)SEQ * NPAIR * 8);
    float*  hid   = (float*) alloc((size_t)256 * DIM * 4);

    k_wconv<<<dim3(24, 8, 4), 256, 0, stream>>>(Wqkv, wqkvt, 512, 1536);
    k_wconv<<<dim3(8, 8, 4),  256, 0, stream>>>(Wo,   wot,   512, 512);
    k_wconv<<<dim3(32, 8, 4), 256, 0, stream>>>(Wm1,  wm1t,  512, 2048);
    k_wconv<<<dim3(8, 32, 4), 256, 0, stream>>>(Wm2,  wm2t,  2048, 512);
    k_rope_tab<<<SEQ, NPAIR, 0, stream>>>(ropet);
    k_in_proj<<<NROW, 256, 0, stream>>>(x, W_in, b_in, cls, hb);

    const int RT = NROW / 128;   // 130
    for (int l = 0; l < NLAYER; l++) {
        k_gemm<32, false, false><<<RT * 12, 512, 0, stream>>>(
            hb, wqkvt + (size_t)l * 1536 * 512, bqkv + l * 1536, nullptr, qkv, 1536, 512);
        k_kvprep<<<BATCH * NHEAD * 9, 256, 0, stream>>>(qkv, ropet, kbuf, vtbuf);
        k_attn_mfma<<<5 * 256, 512, 0, stream>>>(qkv, kbuf, vtbuf, ropet, aob);
        k_gemm64<32, false, true><<<RT * 8, 256, 0, stream>>>(
            aob, wot + (size_t)l * 512 * 512, bo + l * 512, hb, deltab, 512, 512);
        k_ln<<<NROW / 4, 256, 0, stream>>>(hb, deltab, ln1_g + l * 512, ln1_b + l * 512);
        k_gemm<32, true, false><<<RT * 16, 512, 0, stream>>>(
            hb, wm1t + (size_t)l * 2048 * 512, bm1 + l * 2048, nullptr, mid, 2048, 512);
        k_gemm64<64, false, true><<<RT * 8, 256, 0, stream>>>(
            mid, wm2t + (size_t)l * 512 * 2048, bm2 + l * 512, hb, deltab, 512, 2048);
        k_ln<<<NROW / 4, 256, 0, stream>>>(hb, deltab, ln2_g + l * 512, ln2_b + l * 512);
    }

    k_hid<<<dim3(2, 8, 32), 256, 0, stream>>>(hb, Wh, bh, hid);
    k_var<<<256, 64, 0, stream>>>(hid, mu_wmu, mu_wrho, mu_bmu, mu_brho,
                                  lv_wmu, lv_wrho, lv_bmu, lv_brho,
                                  e_mu_w, e_mu_b, e_lv_w, e_lv_b, out);
}

// Round 11
// 1023.074 us; speedup vs baseline: 1.0741x; 1.0134x over previous
//
#include <hip/hip_runtime.h>
#include <cstdint>

// ---------------------------------------------------------------------------
// QRoPETRegressor: 4-layer transformer (B=32, S=520 w/ 8 cls, D=512, NH=8,
// HD=64, MLP=2048) + variational heads.
// R11: fix BK=32 LDS bank conflicts — swizzle XOR uses (row>>1)&3 so the
//      (row-parity, block) pair covers all 8 bank-quads (64B rows alias
//      bank halves; old (row&3) hit only 4 of 8).  Applied stage+read.
// ---------------------------------------------------------------------------

#define BATCH   32
#define SEQ     520
#define SP      576
#define DIM     512
#define NHEAD   8
#define HDIM    64
#define MLPD    2048
#define NLAYER  4
#define NROW    (BATCH * SEQ)   // 16640
#define NPAIR   256

typedef __attribute__((ext_vector_type(4))) float  f32x4;
typedef __attribute__((ext_vector_type(8))) short  short8;

__device__ __forceinline__ unsigned short f2bf(float f) {
    unsigned u = __float_as_uint(f);
    unsigned r = (u + 0x7fffu + ((u >> 16) & 1u)) >> 16;
    return (unsigned short)r;
}
__device__ __forceinline__ float bf2f(short s) {
    return __uint_as_float(((unsigned)(unsigned short)s) << 16);
}
__device__ __forceinline__ unsigned cvt_pk_bf16(float lo, float hi) {
    unsigned r;
    asm("v_cvt_pk_bf16_f32 %0, %1, %2" : "=v"(r) : "v"(lo), "v"(hi));
    return r;
}
__device__ __forceinline__ float exp2_hw(float x) {
    float r;
    asm("v_exp_f32 %0, %1" : "=v"(r) : "v"(x));
    return r;
}
__device__ __forceinline__ float wred_sum(float v) {
    #pragma unroll
    for (int off = 32; off; off >>= 1) v += __shfl_xor(v, off);
    return v;
}

__device__ __forceinline__ void gload16(const void* g, void* l) {
    __builtin_amdgcn_global_load_lds(
        (const __attribute__((address_space(1))) unsigned int*)g,
        (__attribute__((address_space(3))) unsigned int*)l,
        16, 0, 0);
}

// ---------------------------------------------------------------------------
// Weight transpose-convert: src fp32 (K,N) -> dst bf16 (N,K)
// ---------------------------------------------------------------------------
__global__ __launch_bounds__(256) void k_wconv(const float* __restrict__ src,
                                               short* __restrict__ dst,
                                               int K, int N) {
    src += (size_t)blockIdx.z * K * N;
    dst += (size_t)blockIdx.z * K * N;
    int n0 = blockIdx.x * 64, k0 = blockIdx.y * 64;
    __shared__ float t[64][65];
    int tid = threadIdx.x;
    int r = tid >> 2, cq = (tid & 3) * 16;
    const float* sp = src + (size_t)(k0 + r) * N + n0 + cq;
    #pragma unroll
    for (int e = 0; e < 16; e += 4) {
        float4 v = *(const float4*)(sp + e);
        t[r][cq + e] = v.x; t[r][cq + e + 1] = v.y;
        t[r][cq + e + 2] = v.z; t[r][cq + e + 3] = v.w;
    }
    __syncthreads();
    int n = tid >> 2, kq = (tid & 3) * 16;
    short* dp = dst + (size_t)(n0 + n) * K + k0 + kq;
    unsigned o0[4], o1[4];
    #pragma unroll
    for (int e = 0; e < 4; e++)
        o0[e] = cvt_pk_bf16(t[kq + 2 * e][n], t[kq + 2 * e + 1][n]);
    #pragma unroll
    for (int e = 0; e < 4; e++)
        o1[e] = cvt_pk_bf16(t[kq + 8 + 2 * e][n], t[kq + 9 + 2 * e][n]);
    *(uint4*)dp = make_uint4(o0[0], o0[1], o0[2], o0[3]);
    *(uint4*)(dp + 8) = make_uint4(o1[0], o1[1], o1[2], o1[3]);
}

// ---------------------------------------------------------------------------
__global__ void k_rope_tab(float2* __restrict__ tab) {
    int s = blockIdx.x, i = threadIdx.x;
    float fr = powf(10000.f, -2.f * (float)i / 512.f);
    float th = (float)s * fr;
    float sn, cn;
    sincosf(th, &sn, &cn);
    tab[s * NPAIR + i] = make_float2(cn, sn);
}

// ---------------------------------------------------------------------------
// Input proj + cls concat -> bf16 h
// ---------------------------------------------------------------------------
__global__ __launch_bounds__(256) void k_in_proj(const float* __restrict__ x,
                                                 const float* __restrict__ Wi,
                                                 const float* __restrict__ bi,
                                                 const float* __restrict__ cls,
                                                 short* __restrict__ hb) {
    int row = blockIdx.x;
    int b = row / SEQ, s = row % SEQ;
    bool is_cls = s < 8;
    float xr[16];
    if (!is_cls) {
        const float* xp = x + (size_t)(b * 512 + (s - 8)) * 16;
        #pragma unroll
        for (int f = 0; f < 16; f++) xr[f] = xp[f];
    }
    for (int c = threadIdx.x; c < DIM; c += 256) {
        float v;
        if (is_cls) {
            v = cls[s * DIM + c];
        } else {
            v = bi[c];
            #pragma unroll
            for (int f = 0; f < 16; f++) v = fmaf(xr[f], Wi[f * DIM + c], v);
        }
        hb[(size_t)row * DIM + c] = (short)f2bf(v);
    }
}

// ---------------------------------------------------------------------------
// GEMM (128x128 tile, 8 waves): for N >= 1024 shapes (qkv, MLP1).
// Counted-vmcnt depth-2, XOR-swizzle (SH-shifted for BK=32), XCD-chunked.
// ---------------------------------------------------------------------------
template <int BK, bool RELU, bool ADDRES>
__global__ __launch_bounds__(512) void k_gemm(const short* __restrict__ A,
                                              const short* __restrict__ Bt,
                                              const float* __restrict__ bias,
                                              const short* __restrict__ Res,
                                              short* __restrict__ Cout,
                                              int N, int K) {
    constexpr int NB  = BK / 8;
    constexpr int MSK = NB - 1;
    constexpr int SH  = (BK == 32) ? 1 : 0;   // bank-parity-aware swizzle
    constexpr int RPW = 64 / NB;          // rows per gload16
    constexpr int GPM = 128 / (8 * RPW);  // loads per matrix per wave
    constexpr int NLD = 2 * GPM;
    __shared__ __align__(16) short As[2][128 * BK];
    __shared__ __align__(16) short Bs[2][128 * BK];
    const int tid = threadIdx.x;
    const int w = tid >> 6, l = tid & 63;

    const int chunk = gridDim.x >> 3;
    const int t = (blockIdx.x & 7) * chunk + (blockIdx.x >> 3);
    const int C = N >> 7;
    const int brow = (t / C) * 128, bcol = (t % C) * 128;

    const int srow = l / NB;
    const int sblk = l & MSK;
    const int soff = ((sblk ^ ((srow >> SH) & MSK)) * 8);
    const int fr = l & 15, t4 = l >> 4;
    const int wr = (w >> 2) * 64;
    const int wc = (w & 3) * 32;

    const short* Ab = A  + (size_t)(brow + w * RPW + srow) * K + soff;
    const short* Bb = Bt + (size_t)(bcol + w * RPW + srow) * K + soff;

    f32x4 acc[4][2];
    #pragma unroll
    for (int m = 0; m < 4; m++)
        #pragma unroll
        for (int n = 0; n < 2; n++) acc[m][n] = (f32x4){0.f, 0.f, 0.f, 0.f};

    auto stage = [&](int ko, int pb) {
        #pragma unroll
        for (int i = 0; i < GPM; i++)
            gload16(Ab + (size_t)(i * 8 * RPW) * K + ko,
                    &As[pb][(i * 8 * RPW + w * RPW) * BK]);
        #pragma unroll
        for (int i = 0; i < GPM; i++)
            gload16(Bb + (size_t)(i * 8 * RPW) * K + ko,
                    &Bs[pb][(i * 8 * RPW + w * RPW) * BK]);
    };

    const int nk = K / BK;
    stage(0, 0);
    stage(BK, 1);

    for (int kt = 0; kt < nk; ++kt) {
        const int cur = kt & 1;
        if (kt + 1 < nk) {
            if constexpr (NLD == 4) asm volatile("s_waitcnt vmcnt(4)" ::: "memory");
            else                    asm volatile("s_waitcnt vmcnt(2)" ::: "memory");
        } else {
            asm volatile("s_waitcnt vmcnt(0)" ::: "memory");
        }
        __builtin_amdgcn_s_barrier();
        __builtin_amdgcn_sched_barrier(0);

        short8 af[4][BK / 32], bf[2][BK / 32];
        #pragma unroll
        for (int m = 0; m < 4; m++) {
            int r = wr + m * 16 + fr;
            #pragma unroll
            for (int kk = 0; kk < BK / 32; kk++)
                af[m][kk] = *(const short8*)
                    &As[cur][r * BK + (((kk * 4 + t4) ^ ((r >> SH) & MSK)) * 8)];
        }
        #pragma unroll
        for (int n = 0; n < 2; n++) {
            int r = wc + n * 16 + fr;
            #pragma unroll
            for (int kk = 0; kk < BK / 32; kk++)
                bf[n][kk] = *(const short8*)
                    &Bs[cur][r * BK + (((kk * 4 + t4) ^ ((r >> SH) & MSK)) * 8)];
        }
        asm volatile("s_waitcnt lgkmcnt(0)" ::: "memory");
        __builtin_amdgcn_s_barrier();
        __builtin_amdgcn_sched_barrier(0);
        if (kt + 2 < nk) stage((kt + 2) * BK, cur);

        __builtin_amdgcn_s_setprio(1);
        #pragma unroll
        for (int kk = 0; kk < BK / 32; kk++)
            #pragma unroll
            for (int m = 0; m < 4; m++)
                #pragma unroll
                for (int n = 0; n < 2; n++)
                    acc[m][n] = __builtin_amdgcn_mfma_f32_16x16x32_bf16(
                        af[m][kk], bf[n][kk], acc[m][n], 0, 0, 0);
        __builtin_amdgcn_s_setprio(0);
    }

    const int r0 = (l >> 4) * 4, c0 = l & 15;
    #pragma unroll
    for (int m = 0; m < 4; m++) {
        #pragma unroll
        for (int n = 0; n < 2; n++) {
            int col = bcol + wc + n * 16 + c0;
            float bv = bias[col];
            #pragma unroll
            for (int q = 0; q < 4; q++) {
                int row = brow + wr + m * 16 + r0 + q;
                float v = acc[m][n][q] + bv;
                if (ADDRES) v += bf2f(Res[(size_t)row * N + col]);
                if (RELU) v = fmaxf(v, 0.f);
                Cout[(size_t)row * N + col] = (short)f2bf(v);
            }
        }
    }
}

// ---------------------------------------------------------------------------
// GEMM (128x64 tile, 4 waves): for N=512 shapes (Wo, MLP2).
// ---------------------------------------------------------------------------
template <int BK, bool RELU, bool ADDRES>
__global__ __launch_bounds__(256) void k_gemm64(const short* __restrict__ A,
                                                const short* __restrict__ Bt,
                                                const float* __restrict__ bias,
                                                const short* __restrict__ Res,
                                                short* __restrict__ Cout,
                                                int N, int K) {
    constexpr int NB  = BK / 8;
    constexpr int MSK = NB - 1;
    constexpr int SH  = (BK == 32) ? 1 : 0;
    constexpr int RPL = 512 / BK;
    constexpr int ALW = 128 / (4 * RPL);
    constexpr int BLW = 64 / (4 * RPL);
    constexpr int NLD = ALW + BLW;
    __shared__ __align__(16) short As[2][128 * BK];
    __shared__ __align__(16) short Bs[2][64 * BK];
    const int tid = threadIdx.x;
    const int w = tid >> 6, l = tid & 63;

    const int chunk = gridDim.x >> 3;
    const int t = (blockIdx.x & 7) * chunk + (blockIdx.x >> 3);
    const int C = N >> 6;
    const int brow = (t / C) * 128, bcol = (t % C) * 64;

    const int srow = l / NB;
    const int sblk = l & MSK;
    const int soff = ((sblk ^ ((srow >> SH) & MSK)) * 8);
    const int fr = l & 15, t4 = l >> 4;
    const int wr = (w >> 1) * 64;
    const int wc = (w & 1) * 32;

    f32x4 acc[4][2];
    #pragma unroll
    for (int m = 0; m < 4; m++)
        #pragma unroll
        for (int n = 0; n < 2; n++) acc[m][n] = (f32x4){0.f, 0.f, 0.f, 0.f};

    auto stage = [&](int ko, int pb) {
        #pragma unroll
        for (int i = 0; i < ALW; i++)
            gload16(A + (size_t)(brow + (w * ALW + i) * RPL + srow) * K + ko + soff,
                    &As[pb][((w * ALW + i) * RPL) * BK]);
        #pragma unroll
        for (int i = 0; i < BLW; i++)
            gload16(Bt + (size_t)(bcol + (w * BLW + i) * RPL + srow) * K + ko + soff,
                    &Bs[pb][((w * BLW + i) * RPL) * BK]);
    };

    const int nk = K / BK;
    stage(0, 0);
    stage(BK, 1);

    for (int kt = 0; kt < nk; ++kt) {
        const int cur = kt & 1;
        if (kt + 1 < nk) {
            if constexpr (NLD == 3) asm volatile("s_waitcnt vmcnt(3)" ::: "memory");
            else                    asm volatile("s_waitcnt vmcnt(6)" ::: "memory");
        } else {
            asm volatile("s_waitcnt vmcnt(0)" ::: "memory");
        }
        __builtin_amdgcn_s_barrier();
        __builtin_amdgcn_sched_barrier(0);

        short8 af[4][BK / 32], bf[2][BK / 32];
        #pragma unroll
        for (int m = 0; m < 4; m++) {
            int r = wr + m * 16 + fr;
            #pragma unroll
            for (int kk = 0; kk < BK / 32; kk++)
                af[m][kk] = *(const short8*)
                    &As[cur][r * BK + (((kk * 4 + t4) ^ ((r >> SH) & MSK)) * 8)];
        }
        #pragma unroll
        for (int n = 0; n < 2; n++) {
            int r = wc + n * 16 + fr;
            #pragma unroll
            for (int kk = 0; kk < BK / 32; kk++)
                bf[n][kk] = *(const short8*)
                    &Bs[cur][r * BK + (((kk * 4 + t4) ^ ((r >> SH) & MSK)) * 8)];
        }
        asm volatile("s_waitcnt lgkmcnt(0)" ::: "memory");
        __builtin_amdgcn_s_barrier();
        __builtin_amdgcn_sched_barrier(0);
        if (kt + 2 < nk) stage((kt + 2) * BK, cur);

        __builtin_amdgcn_s_setprio(1);
        #pragma unroll
        for (int kk = 0; kk < BK / 32; kk++)
            #pragma unroll
            for (int m = 0; m < 4; m++)
                #pragma unroll
                for (int n = 0; n < 2; n++)
                    acc[m][n] = __builtin_amdgcn_mfma_f32_16x16x32_bf16(
                        af[m][kk], bf[n][kk], acc[m][n], 0, 0, 0);
        __builtin_amdgcn_s_setprio(0);
    }

    const int r0 = (l >> 4) * 4, c0 = l & 15;
    #pragma unroll
    for (int m = 0; m < 4; m++) {
        #pragma unroll
        for (int n = 0; n < 2; n++) {
            int col = bcol + wc + n * 16 + c0;
            float bv = bias[col];
            #pragma unroll
            for (int q = 0; q < 4; q++) {
                int row = brow + wr + m * 16 + r0 + q;
                float v = acc[m][n][q] + bv;
                if (ADDRES) v += bf2f(Res[(size_t)row * N + col]);
                if (RELU) v = fmaxf(v, 0.f);
                Cout[(size_t)row * N + col] = (short)f2bf(v);
            }
        }
    }
}

// ---------------------------------------------------------------------------
// K/V prep: rope K -> kbuf[bh][SP][64]; transpose V -> vtbuf[bh][64][SP].
// ---------------------------------------------------------------------------
__global__ __launch_bounds__(256) void k_kvprep(const short* __restrict__ qkv,
                                                const float2* __restrict__ tab,
                                                short* __restrict__ kbuf,
                                                short* __restrict__ vtbuf) {
    int bx = blockIdx.x;
    int jt = bx % 9, bh = bx / 9, b = bh >> 3, h = bh & 7;
    int tid = threadIdx.x;
    int row = tid >> 2, ch = tid & 3;
    int s = jt * 64 + row;
    bool valid = s < SEQ;
    size_t g = (size_t)(b * SEQ + (valid ? s : 0)) * 1536;

    short8 ok0 = (short8)0, ok1 = (short8)0;
    if (valid) {
        short8 k0 = *(const short8*)(qkv + g + 512 + h * 64 + ch * 16);
        short8 k1 = *(const short8*)(qkv + g + 512 + h * 64 + ch * 16 + 8);
        unsigned* u0 = (unsigned*)&ok0;
        unsigned* u1 = (unsigned*)&ok1;
        #pragma unroll
        for (int pp = 0; pp < 4; pp++) {
            float2 cs = tab[s * NPAIR + h * 32 + ch * 8 + pp];
            float x1 = bf2f(k0[2 * pp]), x2 = bf2f(k0[2 * pp + 1]);
            u0[pp] = cvt_pk_bf16(x1 * cs.x - x2 * cs.y, x1 * cs.y + x2 * cs.x);
            cs = tab[s * NPAIR + h * 32 + ch * 8 + 4 + pp];
            x1 = bf2f(k1[2 * pp]); x2 = bf2f(k1[2 * pp + 1]);
            u1[pp] = cvt_pk_bf16(x1 * cs.x - x2 * cs.y, x1 * cs.y + x2 * cs.x);
        }
    }
    short* kd = kbuf + ((size_t)bh * SP + jt * 64 + row) * 64 + ch * 16;
    *(short8*)kd = ok0;
    *(short8*)(kd + 8) = ok1;

    __shared__ short vt[64][72];
    short8 v0 = (short8)0, v1 = (short8)0;
    if (valid) {
        v0 = *(const short8*)(qkv + g + 1024 + h * 64 + ch * 16);
        v1 = *(const short8*)(qkv + g + 1024 + h * 64 + ch * 16 + 8);
    }
    *(short8*)&vt[row][ch * 16] = v0;
    *(short8*)&vt[row][ch * 16 + 8] = v1;
    __syncthreads();
    int d = row;
    short8 w0, w1;
    #pragma unroll
    for (int e = 0; e < 8; e++) w0[e] = vt[ch * 16 + e][d];
    #pragma unroll
    for (int e = 0; e < 8; e++) w1[e] = vt[ch * 16 + 8 + e][d];
    short* vd = vtbuf + ((size_t)bh * 64 + d) * SP + jt * 64 + ch * 16;
    *(short8*)vd = w0;
    *(short8*)(vd + 8) = w1;
}

// ---------------------------------------------------------------------------
// MFMA flash attention: 8 waves, QBLK=128 (wave w owns q rows qt*128+w*16..).
// K/V staged ONCE per 128 q-rows; counted-vmcnt depth-2; rope fused on Q;
// log2-domain softmax with defer-max + lazy sum.
// grid: bx = qt*256 + bh,  qt in 0..4
// ---------------------------------------------------------------------------
__global__ __launch_bounds__(512) void k_attn_mfma(const short* __restrict__ qkv,
                                                   const short* __restrict__ kbuf,
                                                   const short* __restrict__ vtbuf,
                                                   const float2* __restrict__ tab,
                                                   short* __restrict__ aob) {
    __shared__ __align__(16) short Kl[2][64 * 64];
    __shared__ __align__(16) short Vl[2][64 * 64];
    __shared__ __align__(16) short sP[8][16][72];
    const int tid = threadIdx.x;
    const int w = tid >> 6, l = tid & 63;
    const int c = l & 15, t4 = l >> 4;
    int bx = blockIdx.x;
    int qt = bx >> 8, bh = bx & 255, b = bh >> 3, h = bh & 7;

    const float QSC = 0.125f * 1.44269504f;
    int q0 = qt * 128 + w * 16;
    int qrow = q0 + c;
    int qr = qrow < SEQ ? qrow : SEQ - 1;
    size_t gq = (size_t)(b * SEQ + qr) * 1536 + h * 64;
    short8 qf0 = *(const short8*)(qkv + gq + t4 * 8);
    short8 qf1 = *(const short8*)(qkv + gq + 32 + t4 * 8);
    {
        const float2* tq = tab + (size_t)qr * NPAIR + h * 32;
        unsigned* u0 = (unsigned*)&qf0;
        unsigned* u1 = (unsigned*)&qf1;
        #pragma unroll
        for (int pp = 0; pp < 4; pp++) {
            float2 cs = tq[t4 * 4 + pp];
            float x1 = bf2f(qf0[2 * pp]), x2 = bf2f(qf0[2 * pp + 1]);
            u0[pp] = cvt_pk_bf16((x1 * cs.x - x2 * cs.y) * QSC,
                                 (x1 * cs.y + x2 * cs.x) * QSC);
            cs = tq[16 + t4 * 4 + pp];
            x1 = bf2f(qf1[2 * pp]); x2 = bf2f(qf1[2 * pp + 1]);
            u1[pp] = cvt_pk_bf16((x1 * cs.x - x2 * cs.y) * QSC,
                                 (x1 * cs.y + x2 * cs.x) * QSC);
        }
    }

    f32x4 o0 = {0,0,0,0}, o1 = {0,0,0,0}, o2 = {0,0,0,0}, o3 = {0,0,0,0};
    float mrow[4] = {-1e30f, -1e30f, -1e30f, -1e30f};
    float lrow[4] = {0.f, 0.f, 0.f, 0.f};

    const short* kb = kbuf + (size_t)bh * SP * 64;
    const short* vb = vtbuf + (size_t)bh * 64 * SP;
    const int r1 = w * 8 + (l >> 3);
    const int blk = l & 7;

    auto stage = [&](int jt, int pb) {
        gload16(kb + ((size_t)(jt * 64 + r1)) * 64 + ((blk ^ (r1 & 7)) * 8),
                &Kl[pb][(w * 8) * 64]);
        gload16(vb + (size_t)r1 * SP + jt * 64 + ((blk ^ (r1 & 7)) * 8),
                &Vl[pb][(w * 8) * 64]);
    };

    stage(0, 0);
    stage(1, 1);

    for (int jt = 0; jt < 9; jt++) {
        const int cur = jt & 1;
        if (jt + 1 < 9) asm volatile("s_waitcnt vmcnt(2)" ::: "memory");
        else            asm volatile("s_waitcnt vmcnt(0)" ::: "memory");
        __builtin_amdgcn_s_barrier();
        __builtin_amdgcn_sched_barrier(0);

        f32x4 s0 = {0,0,0,0}, s1 = {0,0,0,0}, s2 = {0,0,0,0}, s3 = {0,0,0,0};
        __builtin_amdgcn_s_setprio(1);
        {
            int kr0 = c, kr1 = 16 + c, kr2 = 32 + c, kr3 = 48 + c;
            short8 kf;
            kf = *(const short8*)&Kl[cur][kr0 * 64 + ((t4 ^ (kr0 & 7)) * 8)];
            s0 = __builtin_amdgcn_mfma_f32_16x16x32_bf16(qf0, kf, s0, 0, 0, 0);
            kf = *(const short8*)&Kl[cur][kr0 * 64 + (((4 + t4) ^ (kr0 & 7)) * 8)];
            s0 = __builtin_amdgcn_mfma_f32_16x16x32_bf16(qf1, kf, s0, 0, 0, 0);
            kf = *(const short8*)&Kl[cur][kr1 * 64 + ((t4 ^ (kr1 & 7)) * 8)];
            s1 = __builtin_amdgcn_mfma_f32_16x16x32_bf16(qf0, kf, s1, 0, 0, 0);
            kf = *(const short8*)&Kl[cur][kr1 * 64 + (((4 + t4) ^ (kr1 & 7)) * 8)];
            s1 = __builtin_amdgcn_mfma_f32_16x16x32_bf16(qf1, kf, s1, 0, 0, 0);
            kf = *(const short8*)&Kl[cur][kr2 * 64 + ((t4 ^ (kr2 & 7)) * 8)];
            s2 = __builtin_amdgcn_mfma_f32_16x16x32_bf16(qf0, kf, s2, 0, 0, 0);
            kf = *(const short8*)&Kl[cur][kr2 * 64 + (((4 + t4) ^ (kr2 & 7)) * 8)];
            s2 = __builtin_amdgcn_mfma_f32_16x16x32_bf16(qf1, kf, s2, 0, 0, 0);
            kf = *(const short8*)&Kl[cur][kr3 * 64 + ((t4 ^ (kr3 & 7)) * 8)];
            s3 = __builtin_amdgcn_mfma_f32_16x16x32_bf16(qf0, kf, s3, 0, 0, 0);
            kf = *(const short8*)&Kl[cur][kr3 * 64 + (((4 + t4) ^ (kr3 & 7)) * 8)];
            s3 = __builtin_amdgcn_mfma_f32_16x16x32_bf16(qf1, kf, s3, 0, 0, 0);
        }
        __builtin_amdgcn_s_setprio(0);

        if (jt == 8) {
            #pragma unroll
            for (int r = 0; r < 4; r++) {
                if (c >= 8) s0[r] = -1e30f;
                s1[r] = -1e30f; s2[r] = -1e30f; s3[r] = -1e30f;
            }
        }

        #pragma unroll
        for (int r = 0; r < 4; r++) {
            float pmax = fmaxf(fmaxf(s0[r], s1[r]), fmaxf(s2[r], s3[r]));
            if (!__all(pmax <= mrow[r] + 8.f)) {
                float mx = pmax;
                mx = fmaxf(mx, __shfl_xor(mx, 1));
                mx = fmaxf(mx, __shfl_xor(mx, 2));
                mx = fmaxf(mx, __shfl_xor(mx, 4));
                mx = fmaxf(mx, __shfl_xor(mx, 8));
                if (mx > mrow[r]) {
                    float sc = exp2_hw(mrow[r] - mx);
                    mrow[r] = mx;
                    lrow[r] *= sc;
                    o0[r] *= sc; o1[r] *= sc; o2[r] *= sc; o3[r] *= sc;
                }
            }
            float p0 = exp2_hw(s0[r] - mrow[r]);
            float p1 = exp2_hw(s1[r] - mrow[r]);
            float p2 = exp2_hw(s2[r] - mrow[r]);
            float p3 = exp2_hw(s3[r] - mrow[r]);
            lrow[r] += (p0 + p1) + (p2 + p3);
            unsigned pk01 = cvt_pk_bf16(p0, p1);
            unsigned pk23 = cvt_pk_bf16(p2, p3);
            int q = t4 * 4 + r;
            sP[w][q][c]      = (short)(pk01 & 0xffff);
            sP[w][q][16 + c] = (short)(pk01 >> 16);
            sP[w][q][32 + c] = (short)(pk23 & 0xffff);
            sP[w][q][48 + c] = (short)(pk23 >> 16);
        }

        __builtin_amdgcn_s_setprio(1);
        {
            short8 pf0 = *(const short8*)&sP[w][c][t4 * 8];
            short8 pf1 = *(const short8*)&sP[w][c][32 + t4 * 8];
            int vr0 = c, vr1 = 16 + c, vr2 = 32 + c, vr3 = 48 + c;
            short8 vf;
            vf = *(const short8*)&Vl[cur][vr0 * 64 + ((t4 ^ (vr0 & 7)) * 8)];
            o0 = __builtin_amdgcn_mfma_f32_16x16x32_bf16(pf0, vf, o0, 0, 0, 0);
            vf = *(const short8*)&Vl[cur][vr0 * 64 + (((4 + t4) ^ (vr0 & 7)) * 8)];
            o0 = __builtin_amdgcn_mfma_f32_16x16x32_bf16(pf1, vf, o0, 0, 0, 0);
            vf = *(const short8*)&Vl[cur][vr1 * 64 + ((t4 ^ (vr1 & 7)) * 8)];
            o1 = __builtin_amdgcn_mfma_f32_16x16x32_bf16(pf0, vf, o1, 0, 0, 0);
            vf = *(const short8*)&Vl[cur][vr1 * 64 + (((4 + t4) ^ (vr1 & 7)) * 8)];
            o1 = __builtin_amdgcn_mfma_f32_16x16x32_bf16(pf1, vf, o1, 0, 0, 0);
            vf = *(const short8*)&Vl[cur][vr2 * 64 + ((t4 ^ (vr2 & 7)) * 8)];
            o2 = __builtin_amdgcn_mfma_f32_16x16x32_bf16(pf0, vf, o2, 0, 0, 0);
            vf = *(const short8*)&Vl[cur][vr2 * 64 + (((4 + t4) ^ (vr2 & 7)) * 8)];
            o2 = __builtin_amdgcn_mfma_f32_16x16x32_bf16(pf1, vf, o2, 0, 0, 0);
            vf = *(const short8*)&Vl[cur][vr3 * 64 + ((t4 ^ (vr3 & 7)) * 8)];
            o3 = __builtin_amdgcn_mfma_f32_16x16x32_bf16(pf0, vf, o3, 0, 0, 0);
            vf = *(const short8*)&Vl[cur][vr3 * 64 + (((4 + t4) ^ (vr3 & 7)) * 8)];
            o3 = __builtin_amdgcn_mfma_f32_16x16x32_bf16(pf1, vf, o3, 0, 0, 0);
        }
        __builtin_amdgcn_s_setprio(0);

        asm volatile("s_waitcnt lgkmcnt(0)" ::: "memory");
        __builtin_amdgcn_s_barrier();
        __builtin_amdgcn_sched_barrier(0);
        if (jt + 2 < 9) stage(jt + 2, cur);
    }

    #pragma unroll
    for (int r = 0; r < 4; r++) {
        float s = lrow[r];
        s += __shfl_xor(s, 1);
        s += __shfl_xor(s, 2);
        s += __shfl_xor(s, 4);
        s += __shfl_xor(s, 8);
        int q = q0 + t4 * 4 + r;
        if (q < SEQ) {
            float inv = 1.f / s;
            short* ao = aob + ((size_t)(b * SEQ + q)) * DIM + h * 64 + c;
            ao[0]  = (short)f2bf(o0[r] * inv);
            ao[16] = (short)f2bf(o1[r] * inv);
            ao[32] = (short)f2bf(o2[r] * inv);
            ao[48] = (short)f2bf(o3[r] * inv);
        }
    }
}

// ---------------------------------------------------------------------------
// LayerNorm (input already contains residual sum): hb = LN(sum)*g + b
// ---------------------------------------------------------------------------
__global__ __launch_bounds__(256) void k_ln(short* __restrict__ hb,
                                            const short* __restrict__ sum,
                                            const float* __restrict__ g,
                                            const float* __restrict__ bta) {
    int row = blockIdx.x * 4 + (threadIdx.x >> 6);
    int l = threadIdx.x & 63;
    size_t base = (size_t)row * DIM + l * 8;
    short8 hv = *(const short8*)&sum[base];
    float a[8];
    float s1 = 0.f, s2 = 0.f;
    #pragma unroll
    for (int e = 0; e < 8; e++) {
        a[e] = bf2f(hv[e]);
        s1 += a[e];
        s2 += a[e] * a[e];
    }
    s1 = wred_sum(s1);
    s2 = wred_sum(s2);
    float mu = s1 * (1.f / 512.f);
    float rr = rsqrtf(s2 * (1.f / 512.f) - mu * mu + 1e-6f);
    float4 g0 = *(const float4*)&g[l * 8];
    float4 g1 = *(const float4*)&g[l * 8 + 4];
    float4 b0 = *(const float4*)&bta[l * 8];
    float4 b1 = *(const float4*)&bta[l * 8 + 4];
    unsigned o[4];
    o[0] = cvt_pk_bf16((a[0] - mu) * rr * g0.x + b0.x,
                       (a[1] - mu) * rr * g0.y + b0.y);
    o[1] = cvt_pk_bf16((a[2] - mu) * rr * g0.z + b0.z,
                       (a[3] - mu) * rr * g0.w + b0.w);
    o[2] = cvt_pk_bf16((a[4] - mu) * rr * g1.x + b1.x,
                       (a[5] - mu) * rr * g1.y + b1.y);
    o[3] = cvt_pk_bf16((a[6] - mu) * rr * g1.z + b1.z,
                       (a[7] - mu) * rr * g1.w + b1.w);
    *(uint4*)&hb[base] = make_uint4(o[0], o[1], o[2], o[3]);
}

// ---------------------------------------------------------------------------
// Head hidden: hid[b,o,j] = relu(x_cls[b,o,:] @ Wh[o] + bh[o,j])
// ---------------------------------------------------------------------------
__global__ __launch_bounds__(256) void k_hid(const short* __restrict__ hb,
                                             const float* __restrict__ Wh,
                                             const float* __restrict__ bh,
                                             float* __restrict__ hid) {
    int j = blockIdx.x * 256 + threadIdx.x;
    int o = blockIdx.y, b = blockIdx.z;
    const short* xr = hb + ((size_t)(b * SEQ + o)) * DIM;
    const float* wcol = Wh + (size_t)o * DIM * DIM + j;
    float acc = bh[o * DIM + j];
    #pragma unroll 8
    for (int d = 0; d < DIM; d++)
        acc = fmaf(bf2f(xr[d]), wcol[(size_t)d * DIM], acc);
    hid[((size_t)b * 8 + o) * DIM + j] = fmaxf(acc, 0.f);
}

// ---------------------------------------------------------------------------
__device__ __forceinline__ float softplus_f(float x) { return log1pf(expf(x)); }

__global__ __launch_bounds__(64) void k_var(const float* __restrict__ hid,
                                            const float* __restrict__ mu_wmu,
                                            const float* __restrict__ mu_wrho,
                                            const float* __restrict__ mu_bmu,
                                            const float* __restrict__ mu_brho,
                                            const float* __restrict__ lv_wmu,
                                            const float* __restrict__ lv_wrho,
                                            const float* __restrict__ lv_bmu,
                                            const float* __restrict__ lv_brho,
                                            const float* __restrict__ eps_mu_w,
                                            const float* __restrict__ eps_mu_b,
                                            const float* __restrict__ eps_lv_w,
                                            const float* __restrict__ eps_lv_b,
                                            float* __restrict__ out) {
    const float EPS = 1e-8f;
    int bo = blockIdx.x;
    int o = bo & 7;
    int l = threadIdx.x;
    float am = 0.f, al = 0.f;
    #pragma unroll
    for (int k = 0; k < 8; k++) {
        int d = k * 64 + l;
        int od = o * DIM + d;
        float hv = hid[(size_t)bo * DIM + d];
        am = fmaf(hv, mu_wmu[od] + (softplus_f(mu_wrho[od]) + EPS) * eps_mu_w[od], am);
        al = fmaf(hv, lv_wmu[od] + (softplus_f(lv_wrho[od]) + EPS) * eps_lv_w[od], al);
    }
    am = wred_sum(am);
    al = wred_sum(al);
    if (l == 0) {
        float mu = am + mu_bmu[o] + (softplus_f(mu_brho[o]) + EPS) * eps_mu_b[o];
        out[bo] = mu;
        float lvv = al + lv_bmu[o] + (softplus_f(lv_brho[o]) + EPS) * eps_lv_b[o];
        out[256 + bo] = logf(EPS + softplus_f(lvv));
    }
}

// ---------------------------------------------------------------------------
extern "C" void kernel_launch(void* const* d_in, const int* in_sizes, int n_in,
                              void* d_out, int out_size, void* d_ws, size_t ws_size,
                              hipStream_t stream) {
    const float* x      = (const float*)d_in[0];
    const float* W_in   = (const float*)d_in[1];
    const float* b_in   = (const float*)d_in[2];
    const float* cls    = (const float*)d_in[3];
    const float* Wqkv   = (const float*)d_in[4];
    const float* bqkv   = (const float*)d_in[5];
    const float* Wo     = (const float*)d_in[6];
    const float* bo     = (const float*)d_in[7];
    const float* ln1_g  = (const float*)d_in[8];
    const float* ln1_b  = (const float*)d_in[9];
    const float* Wm1    = (const float*)d_in[10];
    const float* bm1    = (const float*)d_in[11];
    const float* Wm2    = (const float*)d_in[12];
    const float* bm2    = (const float*)d_in[13];
    const float* ln2_g  = (const float*)d_in[14];
    const float* ln2_b  = (const float*)d_in[15];
    const float* Wh     = (const float*)d_in[16];
    const float* bh     = (const float*)d_in[17];
    const float* mu_wmu = (const float*)d_in[18];
    const float* mu_wrho= (const float*)d_in[19];
    const float* mu_bmu = (const float*)d_in[20];
    const float* mu_brho= (const float*)d_in[21];
    const float* lv_wmu = (const float*)d_in[22];
    const float* lv_wrho= (const float*)d_in[23];
    const float* lv_bmu = (const float*)d_in[24];
    const float* lv_brho= (const float*)d_in[25];
    const float* e_mu_w = (const float*)d_in[26];
    const float* e_mu_b = (const float*)d_in[27];
    const float* e_lv_w = (const float*)d_in[28];
    const float* e_lv_b = (const float*)d_in[29];
    float* out = (float*)d_out;

    char* p = (char*)d_ws;
    auto alloc = [&](size_t bytes) {
        char* r = p;
        p += (bytes + 255) & ~(size_t)255;
        return r;
    };
    const size_t qkv_bytes = (size_t)NROW * 1536 * 2;
    const size_t kbuf_bytes = (size_t)BATCH * NHEAD * SP * 64 * 2;
    const size_t attn_bytes = qkv_bytes + 2 * kbuf_bytes + 512;
    const size_t mid_bytes = (size_t)NROW * MLPD * 2;
    char*   U1    =          alloc(attn_bytes > mid_bytes ? attn_bytes : mid_bytes);
    short*  qkv   = (short*)U1;
    short*  kbuf  = (short*)(U1 + ((qkv_bytes + 255) & ~(size_t)255));
    short*  vtbuf = kbuf + kbuf_bytes / 2;
    short*  mid   = (short*)U1;
    short*  hb    = (short*) alloc((size_t)NROW * DIM * 2);
    short*  deltab= (short*) alloc((size_t)NROW * DIM * 2);
    short*  aob   = (short*) alloc((size_t)NROW * DIM * 2);
    short*  wqkvt = (short*) alloc((size_t)NLAYER * 1536 * 512 * 2);
    short*  wot   = (short*) alloc((size_t)NLAYER * 512 * 512 * 2);
    short*  wm1t  = (short*) alloc((size_t)NLAYER * 2048 * 512 * 2);
    short*  wm2t  = (short*) alloc((size_t)NLAYER * 512 * 2048 * 2);
    float2* ropet = (float2*)alloc((size_t)SEQ * NPAIR * 8);
    float*  hid   = (float*) alloc((size_t)256 * DIM * 4);

    k_wconv<<<dim3(24, 8, 4), 256, 0, stream>>>(Wqkv, wqkvt, 512, 1536);
    k_wconv<<<dim3(8, 8, 4),  256, 0, stream>>>(Wo,   wot,   512, 512);
    k_wconv<<<dim3(32, 8, 4), 256, 0, stream>>>(Wm1,  wm1t,  512, 2048);
    k_wconv<<<dim3(8, 32, 4), 256, 0, stream>>>(Wm2,  wm2t,  2048, 512);
    k_rope_tab<<<SEQ, NPAIR, 0, stream>>>(ropet);
    k_in_proj<<<NROW, 256, 0, stream>>>(x, W_in, b_in, cls, hb);

    const int RT = NROW / 128;   // 130
    for (int l = 0; l < NLAYER; l++) {
        k_gemm<32, false, false><<<RT * 12, 512, 0, stream>>>(
            hb, wqkvt + (size_t)l * 1536 * 512, bqkv + l * 1536, nullptr, qkv, 1536, 512);
        k_kvprep<<<BATCH * NHEAD * 9, 256, 0, stream>>>(qkv, ropet, kbuf, vtbuf);
        k_attn_mfma<<<5 * 256, 512, 0, stream>>>(qkv, kbuf, vtbuf, ropet, aob);
        k_gemm64<32, false, true><<<RT * 8, 256, 0, stream>>>(
            aob, wot + (size_t)l * 512 * 512, bo + l * 512, hb, deltab, 512, 512);
        k_ln<<<NROW / 4, 256, 0, stream>>>(hb, deltab, ln1_g + l * 512, ln1_b + l * 512);
        k_gemm<32, true, false><<<RT * 16, 512, 0, stream>>>(
            hb, wm1t + (size_t)l * 2048 * 512, bm1 + l * 2048, nullptr, mid, 2048, 512);
        k_gemm64<64, false, true><<<RT * 8, 256, 0, stream>>>(
            mid, wm2t + (size_t)l * 512 * 2048, bm2 + l * 512, hb, deltab, 512, 2048);
        k_ln<<<NROW / 4, 256, 0, stream>>>(hb, deltab, ln2_g + l * 512, ln2_b + l * 512);
    }

    k_hid<<<dim3(2, 8, 32), 256, 0, stream>>>(hb, Wh, bh, hid);
    k_var<<<256, 64, 0, stream>>>(hid, mu_wmu, mu_wrho, mu_bmu, mu_brho,
                                  lv_wmu, lv_wrho, lv_bmu, lv_brho,
                                  e_mu_w, e_mu_b, e_lv_w, e_lv_b, out);
}